// Round 1
// baseline (651.971 us; speedup 1.0000x reference)
//
#include <hip/hip_runtime.h>
#include <math.h>

#define N_NODES 50000
#define N_EDGES 800000
#define HIDC 32
#define HEADS 8
#define F0 256            // HID*HEADS
#define OUTD 16
#define NEG_SLOPE 0.2f
#define LN_EPS 1e-5f
#define NB0 196           // ceil(N/256)

// ---------------- h0 = x @ Win + bin  ([N,1]x[1,32]) ----------------
__global__ __launch_bounds__(256) void k_h0(const float* __restrict__ x,
                                            const float* __restrict__ Win,
                                            const float* __restrict__ bin,
                                            float* __restrict__ h0) {
    int idx = blockIdx.x * 256 + threadIdx.x;
    if (idx >= N_NODES * HIDC) return;
    int i = idx >> 5, j = idx & 31;
    h0[idx] = fmaf(x[i], Win[j], bin[j]);
}

// ------------- layer0 linears: res0 = h0@Wr0+br0, hW0 = h0@W0, a_s/a_d -------------
// block = 256 threads (one output column each), 32 nodes per block, weights in VGPRs
__global__ __launch_bounds__(256) void k_lin0(const float* __restrict__ h0,
    const float* __restrict__ Wr0, const float* __restrict__ br0,
    const float* __restrict__ W0,  const float* __restrict__ as0,
    const float* __restrict__ ad0,
    float* __restrict__ res0, float* __restrict__ hW0,
    float* __restrict__ a_s0, float* __restrict__ a_d0) {
    const int t = threadIdx.x;
    const int base = blockIdx.x * 32;
    __shared__ float lh[32 * 32];
    float wr[32], wc[32];
#pragma unroll
    for (int k = 0; k < 32; k++) { wr[k] = Wr0[k * 256 + t]; wc[k] = W0[k * 256 + t]; }
    const float brv = br0[t], asv = as0[t], adv = ad0[t];
    for (int v = t; v < 1024; v += 256) {
        int g = base * 32 + v;
        lh[v] = (g < N_NODES * 32) ? h0[g] : 0.f;
    }
    __syncthreads();
    int mmax = min(32, N_NODES - base);
    for (int m = 0; m < mmax; m++) {
        int node = base + m;
        float ar = brv, aw = 0.f;
#pragma unroll
        for (int k = 0; k < 32; k++) {
            float xv = lh[m * 32 + k];
            ar = fmaf(xv, wr[k], ar);
            aw = fmaf(xv, wc[k], aw);
        }
        res0[node * 256 + t] = ar;
        hW0[node * 256 + t] = aw;
        float ps = aw * asv, pd = aw * adv;
#pragma unroll
        for (int o = 16; o >= 1; o >>= 1) { ps += __shfl_xor(ps, o); pd += __shfl_xor(pd, o); }
        if ((t & 31) == 0) { a_s0[node * 8 + (t >> 5)] = ps; a_d0[node * 8 + (t >> 5)] = pd; }
    }
}

// ---------------- CSR build by dst ----------------
__global__ __launch_bounds__(256) void k_deg_init(int* deg) {
    int i = blockIdx.x * 256 + threadIdx.x;
    if (i < N_NODES) deg[i] = 1;   // self-loop
}
__global__ __launch_bounds__(256) void k_deg_count(const int* __restrict__ dstA, int* deg) {
    int e = blockIdx.x * 256 + threadIdx.x;
    if (e < N_EDGES) atomicAdd(&deg[dstA[e]], 1);
}
__global__ __launch_bounds__(256) void k_scan1(const int* __restrict__ deg,
                                               int* __restrict__ rowstart, int* __restrict__ bsum) {
    __shared__ int s[256];
    int t = threadIdx.x;
    int i = blockIdx.x * 256 + t;
    int v = (i < N_NODES) ? deg[i] : 0;
    s[t] = v; __syncthreads();
    for (int o = 1; o < 256; o <<= 1) {
        int xv = (t >= o) ? s[t - o] : 0;
        __syncthreads();
        s[t] += xv;
        __syncthreads();
    }
    if (i < N_NODES) rowstart[i] = s[t] - v;
    if (t == 255) bsum[blockIdx.x] = s[255];
}
__global__ __launch_bounds__(256) void k_scan2(const int* __restrict__ bsum,
                                               int* __restrict__ rowstart, int* __restrict__ boff) {
    __shared__ int s[256];
    int t = threadIdx.x;
    int v = (t < NB0) ? bsum[t] : 0;
    s[t] = v; __syncthreads();
    for (int o = 1; o < 256; o <<= 1) {
        int xv = (t >= o) ? s[t - o] : 0;
        __syncthreads();
        s[t] += xv;
        __syncthreads();
    }
    if (t < NB0) boff[t] = s[t] - v;
    if (t == 255) rowstart[N_NODES] = s[255];   // = E + N
}
__global__ __launch_bounds__(256) void k_scan3(int* __restrict__ rowstart,
                                               const int* __restrict__ boff, int* __restrict__ cursor) {
    int t = threadIdx.x;
    int i = blockIdx.x * 256 + t;
    if (i < N_NODES) {
        int r = rowstart[i] + boff[blockIdx.x];
        rowstart[i] = r;
        cursor[i] = r;
    }
}
__global__ __launch_bounds__(256) void k_scatter(const int* __restrict__ srcA,
                                                 const int* __restrict__ dstA,
                                                 int* cursor, int* __restrict__ csr) {
    int e = blockIdx.x * 256 + threadIdx.x;
    if (e < N_EDGES) {
        int d = dstA[e];
        int p = atomicAdd(&cursor[d], 1);
        csr[p] = srcA[e];
    }
}
__global__ __launch_bounds__(256) void k_scatter_loops(int* cursor, int* __restrict__ csr) {
    int i = blockIdx.x * 256 + threadIdx.x;
    if (i < N_NODES) {
        int p = atomicAdd(&cursor[i], 1);
        csr[p] = i;
    }
}

// -------- layer0 aggregation + bias + elu + residual + LayerNorm (fused) --------
// one block (256 thr) per node; thread t: head = t>>5, feat = t&31
__global__ __launch_bounds__(256) void k_agg0(const int* __restrict__ rowstart,
    const int* __restrict__ csr,
    const float* __restrict__ a_s0, const float* __restrict__ a_d0,
    const float* __restrict__ hW0, const float* __restrict__ bg0,
    const float* __restrict__ g0, const float* __restrict__ b0,
    float* __restrict__ resio /* in: res0, out: h1 (in-place) */) {
    const int i = blockIdx.x;
    const int t = threadIdx.x;
    const int h = t >> 5;
    __shared__ float red[4];
    const float adi = a_d0[i * 8 + h];
    const int jb = rowstart[i], je = rowstart[i + 1];
    float m = -3.4e38f, l = 0.f, acc = 0.f;
    for (int j = jb; j < je; j++) {
        int s = csr[j];
        float e = a_s0[s * 8 + h] + adi;
        e = (e > 0.f) ? e : NEG_SLOPE * e;
        float nm = fmaxf(m, e);
        float sc = __expf(m - nm);
        float p = __expf(e - nm);
        l = l * sc + p;
        acc = acc * sc + p * hW0[s * 256 + t];
        m = nm;
    }
    float val = acc / (l + 1e-16f) + bg0[t];
    val = (val > 0.f) ? val : expm1f(val);            // ELU
    val += resio[i * 256 + t];                        // residual
    // LayerNorm over 256 (two-pass)
    float v = val;
#pragma unroll
    for (int o = 32; o >= 1; o >>= 1) v += __shfl_xor(v, o);
    if ((t & 63) == 0) red[t >> 6] = v;
    __syncthreads();
    float mean = (red[0] + red[1] + red[2] + red[3]) * (1.f / 256.f);
    __syncthreads();
    float d = val - mean;
    v = d * d;
#pragma unroll
    for (int o = 32; o >= 1; o >>= 1) v += __shfl_xor(v, o);
    if ((t & 63) == 0) red[t >> 6] = v;
    __syncthreads();
    float var = (red[0] + red[1] + red[2] + red[3]) * (1.f / 256.f);
    resio[i * 256 + t] = d * rsqrtf(var + LN_EPS) * g0[t] + b0[t];
}

// ------------- layer1 linears: res1 = h1@Wr1+br1, hW1 = h1@W1, a_s1/a_d1 -------------
// block 256 = 8 kChunks x 32 cols; each thread holds a 32-row weight slice in VGPRs
__global__ __launch_bounds__(256) void k_lin1(const float* __restrict__ h1,
    const float* __restrict__ Wr1, const float* __restrict__ br1,
    const float* __restrict__ W1,  const float* __restrict__ as1,
    const float* __restrict__ ad1,
    float* __restrict__ res1, float* __restrict__ hW1,
    float* __restrict__ a_s1, float* __restrict__ a_d1) {
    const int t = threadIdx.x;
    const int kc = t >> 5, col = t & 31;
    float wr[32], wc[32];
#pragma unroll
    for (int j = 0; j < 32; j++) {
        wr[j] = Wr1[(kc * 32 + j) * 32 + col];
        wc[j] = W1[(kc * 32 + j) * 32 + col];
    }
    __shared__ float lh[256];
    __shared__ float pr[256], pw[256];
    const int base = blockIdx.x * 64;
    const int mmax = min(64, N_NODES - base);
    for (int m = 0; m < mmax; m++) {
        int node = base + m;
        lh[t] = h1[node * 256 + t];
        __syncthreads();
        float sr = 0.f, sw = 0.f;
#pragma unroll
        for (int j = 0; j < 32; j++) {
            float xv = lh[kc * 32 + j];
            sr = fmaf(xv, wr[j], sr);
            sw = fmaf(xv, wc[j], sw);
        }
        pr[t] = sr; pw[t] = sw;
        __syncthreads();
        if (t < 32) {
            float r = br1[t], w = 0.f;
#pragma unroll
            for (int k = 0; k < 8; k++) { r += pr[k * 32 + t]; w += pw[k * 32 + t]; }
            res1[node * 32 + t] = r;
            hW1[node * 32 + t] = w;
            float ps = w * as1[t], pd = w * ad1[t];
#pragma unroll
            for (int o = 16; o >= 1; o >>= 1) { ps += __shfl_xor(ps, o); pd += __shfl_xor(pd, o); }
            if (t == 0) { a_s1[node] = ps; a_d1[node] = pd; }
        }
        __syncthreads();
    }
}

// -------- layer1 aggregation (heads=1) + bias + residual + LayerNorm --------
// block 256 = 8 nodes x 32 feats
__global__ __launch_bounds__(256) void k_agg1(const int* __restrict__ rowstart,
    const int* __restrict__ csr,
    const float* __restrict__ a_s1, const float* __restrict__ a_d1,
    const float* __restrict__ hW1, const float* __restrict__ bg1,
    const float* __restrict__ res1, const float* __restrict__ g1,
    const float* __restrict__ b1, float* __restrict__ h2) {
    const int t = threadIdx.x;
    const int sub = t >> 5, f = t & 31;
    const int i = blockIdx.x * 8 + sub;
    if (i >= N_NODES) return;
    const float adi = a_d1[i];
    const int jb = rowstart[i], je = rowstart[i + 1];
    float m = -3.4e38f, l = 0.f, acc = 0.f;
    for (int j = jb; j < je; j++) {
        int s = csr[j];
        float e = a_s1[s] + adi;
        e = (e > 0.f) ? e : NEG_SLOPE * e;
        float nm = fmaxf(m, e);
        float sc = __expf(m - nm);
        float p = __expf(e - nm);
        l = l * sc + p;
        acc = acc * sc + p * hW1[s * 32 + f];
        m = nm;
    }
    float val = acc / (l + 1e-16f) + bg1[f] + res1[i * 32 + f];
    float s1 = val;
#pragma unroll
    for (int o = 16; o >= 1; o >>= 1) s1 += __shfl_xor(s1, o);
    float mean = s1 * (1.f / 32.f);
    float d = val - mean;
    float s2 = d * d;
#pragma unroll
    for (int o = 16; o >= 1; o >>= 1) s2 += __shfl_xor(s2, o);
    float var = s2 * (1.f / 32.f);
    h2[i * 32 + f] = d * rsqrtf(var + LN_EPS) * g1[f] + b1[f];
}

// ---------------- global mean pool partials ----------------
__global__ __launch_bounds__(256) void k_pool(const float* __restrict__ h2, float* __restrict__ partial) {
    const int t = threadIdx.x;
    const int col = t & 31, sub = t >> 5;
    float acc = 0.f;
    for (int i = blockIdx.x * 8 + sub; i < N_NODES; i += 64 * 8) acc += h2[i * 32 + col];
    __shared__ float s[256];
    s[t] = acc; __syncthreads();
    if (t < 32) {
        float a = 0.f;
        for (int k = 0; k < 8; k++) a += s[k * 32 + t];
        partial[blockIdx.x * 32 + t] = a;
    }
}

// ---------------- final: pooled @ Wout + bout ----------------
__global__ __launch_bounds__(64) void k_final(const float* __restrict__ partial,
                                              const float* __restrict__ Wout,
                                              const float* __restrict__ bout,
                                              float* __restrict__ out) {
    __shared__ float pooled[32];
    int t = threadIdx.x;
    if (t < 32) {
        float a = 0.f;
        for (int b = 0; b < 64; b++) a += partial[b * 32 + t];
        pooled[t] = a * (1.f / (float)N_NODES);
    }
    __syncthreads();
    if (t < OUTD) {
        float o = bout[t];
        for (int c = 0; c < 32; c++) o = fmaf(pooled[c], Wout[c * OUTD + t], o);
        out[t] = o;
    }
}

extern "C" void kernel_launch(void* const* d_in, const int* in_sizes, int n_in,
                              void* d_out, int out_size, void* d_ws, size_t ws_size,
                              hipStream_t stream) {
    const float* x    = (const float*)d_in[0];
    const int*   eidx = (const int*)d_in[1];      // [0,E)=src, [E,2E)=dst
    const float* Win  = (const float*)d_in[3];
    const float* bin  = (const float*)d_in[4];
    const float* Wr0  = (const float*)d_in[5];
    const float* br0  = (const float*)d_in[6];
    const float* W0   = (const float*)d_in[7];
    const float* as0  = (const float*)d_in[8];
    const float* ad0  = (const float*)d_in[9];
    const float* bg0  = (const float*)d_in[10];
    const float* g0   = (const float*)d_in[11];
    const float* b0   = (const float*)d_in[12];
    const float* Wr1  = (const float*)d_in[13];
    const float* br1  = (const float*)d_in[14];
    const float* W1   = (const float*)d_in[15];
    const float* as1  = (const float*)d_in[16];
    const float* ad1  = (const float*)d_in[17];
    const float* bg1  = (const float*)d_in[18];
    const float* g1   = (const float*)d_in[19];
    const float* b1   = (const float*)d_in[20];
    const float* Wout = (const float*)d_in[21];
    const float* bout = (const float*)d_in[22];
    float* out = (float*)d_out;

    const int* srcA = eidx;
    const int* dstA = eidx + N_EDGES;

    // workspace layout (floats)
    float* ws = (float*)d_ws;
    float* h0   = ws;                         // N*32
    float* res0 = h0 + (size_t)N_NODES * 32;  // N*256   (becomes h1 in-place)
    float* hW0  = res0 + (size_t)N_NODES * 256; // N*256 (region reused for layer1 temps)
    float* a_s0 = hW0 + (size_t)N_NODES * 256;  // N*8
    float* a_d0 = a_s0 + (size_t)N_NODES * 8;   // N*8
    // layer1 temps reuse hW0's region after agg0 completes? NO — hW0 needed until agg0;
    // k_lin1 runs after k_agg0, so reuse is safe:
    float* res1 = hW0;                           // N*32
    float* hW1  = hW0 + (size_t)N_NODES * 32;    // N*32
    float* a_s1 = hW0 + (size_t)N_NODES * 64;    // N
    float* a_d1 = a_s1 + N_NODES;                // N
    float* h2   = hW0 + (size_t)N_NODES * 66;    // N*32
    float* partial = hW0 + (size_t)N_NODES * 98; // 64*32
    int* ibase   = (int*)(a_d0 + (size_t)N_NODES * 8);
    int* rowstart = ibase;                 // N+1
    int* cursor   = rowstart + N_NODES + 1;
    int* bsum     = cursor + N_NODES;      // NB0
    int* boff     = bsum + NB0;            // NB0
    int* csr      = boff + NB0;            // E+N
    int* deg      = csr + (N_EDGES + N_NODES); // N (separate from rowstart)

    // dense front
    k_h0<<<(N_NODES * 32 + 255) / 256, 256, 0, stream>>>(x, Win, bin, h0);
    k_lin0<<<(N_NODES + 31) / 32, 256, 0, stream>>>(h0, Wr0, br0, W0, as0, ad0,
                                                    res0, hW0, a_s0, a_d0);
    // CSR build
    k_deg_init<<<NB0, 256, 0, stream>>>(deg);
    k_deg_count<<<(N_EDGES + 255) / 256, 256, 0, stream>>>(dstA, deg);
    k_scan1<<<NB0, 256, 0, stream>>>(deg, rowstart, bsum);
    k_scan2<<<1, 256, 0, stream>>>(bsum, rowstart, boff);
    k_scan3<<<NB0, 256, 0, stream>>>(rowstart, boff, cursor);
    k_scatter<<<(N_EDGES + 255) / 256, 256, 0, stream>>>(srcA, dstA, cursor, csr);
    k_scatter_loops<<<NB0, 256, 0, stream>>>(cursor, csr);
    // layer 0 aggregation (fused epilogue), h1 written over res0
    k_agg0<<<N_NODES, 256, 0, stream>>>(rowstart, csr, a_s0, a_d0, hW0, bg0, g0, b0, res0);
    // layer 1
    k_lin1<<<(N_NODES + 63) / 64, 256, 0, stream>>>(res0, Wr1, br1, W1, as1, ad1,
                                                    res1, hW1, a_s1, a_d1);
    k_agg1<<<(N_NODES + 7) / 8, 256, 0, stream>>>(rowstart, csr, a_s1, a_d1, hW1,
                                                  bg1, res1, g1, b1, h2);
    // pool + head
    k_pool<<<64, 256, 0, stream>>>(h2, partial);
    k_final<<<1, 64, 0, stream>>>(partial, Wout, bout, out);
}

// Round 2
// 532.788 us; speedup vs baseline: 1.2237x; 1.2237x over previous
//
#include <hip/hip_runtime.h>
#include <math.h>

#define N_NODES 50000
#define N_EDGES 800000
#define HEADS 8
#define OUTD 16
#define NEG_SLOPE 0.2f
#define LN_EPS 1e-5f
#define NB0 196           // ceil(N/256)

// ------------- layer0: h0 = x*Win+bin computed on the fly; res0 = h0@Wr0+br0,
// hW0 = h0@W0, attention dots a_s0/a_d0. 256 thr = one output col each, 32 nodes/block.
__global__ __launch_bounds__(256) void k_lin0(const float* __restrict__ x,
    const float* __restrict__ Win, const float* __restrict__ bin,
    const float* __restrict__ Wr0, const float* __restrict__ br0,
    const float* __restrict__ W0,  const float* __restrict__ as0,
    const float* __restrict__ ad0,
    float* __restrict__ res0, float* __restrict__ hW0,
    float* __restrict__ a_s0, float* __restrict__ a_d0) {
    const int t = threadIdx.x;
    const int base = blockIdx.x * 32;
    __shared__ float sx[32];
    __shared__ float lh[32 * 32];
    float wr[32], wc[32];
#pragma unroll
    for (int k = 0; k < 32; k++) { wr[k] = Wr0[k * 256 + t]; wc[k] = W0[k * 256 + t]; }
    const float brv = br0[t], asv = as0[t], adv = ad0[t];
    if (t < 32) sx[t] = (base + t < N_NODES) ? x[base + t] : 0.f;
    __syncthreads();
    const float winv = Win[t & 31], binv = bin[t & 31];
    for (int idx = t; idx < 1024; idx += 256) {
        int m = idx >> 5;
        lh[idx] = fmaf(sx[m], winv, binv);
    }
    __syncthreads();
    int mmax = min(32, N_NODES - base);
    for (int m = 0; m < mmax; m++) {
        int node = base + m;
        const float4* lp = (const float4*)(lh + m * 32);
        float ar = brv, aw = 0.f;
#pragma unroll
        for (int q = 0; q < 8; q++) {
            float4 v = lp[q];
            ar = fmaf(v.x, wr[4*q+0], ar); aw = fmaf(v.x, wc[4*q+0], aw);
            ar = fmaf(v.y, wr[4*q+1], ar); aw = fmaf(v.y, wc[4*q+1], aw);
            ar = fmaf(v.z, wr[4*q+2], ar); aw = fmaf(v.z, wc[4*q+2], aw);
            ar = fmaf(v.w, wr[4*q+3], ar); aw = fmaf(v.w, wc[4*q+3], aw);
        }
        res0[node * 256 + t] = ar;
        hW0[node * 256 + t] = aw;
        float ps = aw * asv, pd = aw * adv;
#pragma unroll
        for (int o = 16; o >= 1; o >>= 1) { ps += __shfl_xor(ps, o); pd += __shfl_xor(pd, o); }
        if ((t & 31) == 0) { a_s0[node * 8 + (t >> 5)] = ps; a_d0[node * 8 + (t >> 5)] = pd; }
    }
}

// ---------------- CSR build by dst ----------------
__global__ __launch_bounds__(256) void k_deg_init(int* deg) {
    int i = blockIdx.x * 256 + threadIdx.x;
    if (i < N_NODES) deg[i] = 1;   // self-loop
}
__global__ __launch_bounds__(256) void k_deg_count(const int* __restrict__ dstA, int* deg) {
    int e = blockIdx.x * 256 + threadIdx.x;
    if (e < N_EDGES) atomicAdd(&deg[dstA[e]], 1);
}
__global__ __launch_bounds__(256) void k_scan1(const int* __restrict__ deg,
                                               int* __restrict__ rowstart, int* __restrict__ bsum) {
    __shared__ int s[256];
    int t = threadIdx.x;
    int i = blockIdx.x * 256 + t;
    int v = (i < N_NODES) ? deg[i] : 0;
    s[t] = v; __syncthreads();
    for (int o = 1; o < 256; o <<= 1) {
        int xv = (t >= o) ? s[t - o] : 0;
        __syncthreads();
        s[t] += xv;
        __syncthreads();
    }
    if (i < N_NODES) rowstart[i] = s[t] - v;
    if (t == 255) bsum[blockIdx.x] = s[255];
}
__global__ __launch_bounds__(256) void k_scan2(const int* __restrict__ bsum,
                                               int* __restrict__ rowstart, int* __restrict__ boff) {
    __shared__ int s[256];
    int t = threadIdx.x;
    int v = (t < NB0) ? bsum[t] : 0;
    s[t] = v; __syncthreads();
    for (int o = 1; o < 256; o <<= 1) {
        int xv = (t >= o) ? s[t - o] : 0;
        __syncthreads();
        s[t] += xv;
        __syncthreads();
    }
    if (t < NB0) boff[t] = s[t] - v;
    if (t == 255) rowstart[N_NODES] = s[255];   // = E + N
}
__global__ __launch_bounds__(256) void k_scan3(int* __restrict__ rowstart,
                                               const int* __restrict__ boff, int* __restrict__ cursor) {
    int t = threadIdx.x;
    int i = blockIdx.x * 256 + t;
    if (i < N_NODES) {
        int r = rowstart[i] + boff[blockIdx.x];
        rowstart[i] = r;
        cursor[i] = r;
    }
}
__global__ __launch_bounds__(256) void k_scatter(const int* __restrict__ srcA,
                                                 const int* __restrict__ dstA,
                                                 int* cursor, int* __restrict__ csr) {
    int e = blockIdx.x * 256 + threadIdx.x;
    if (e < N_EDGES) {
        int d = dstA[e];
        int p = atomicAdd(&cursor[d], 1);
        csr[p] = srcA[e];
    }
}
__global__ __launch_bounds__(256) void k_scatter_loops(int* cursor, int* __restrict__ csr) {
    int i = blockIdx.x * 256 + threadIdx.x;
    if (i < N_NODES) {
        int p = atomicAdd(&cursor[i], 1);
        csr[p] = i;
    }
}

// -------- layer0 softmax weights: one wave (64 thr) per node; slot=t>>3, h=t&7 --------
__global__ __launch_bounds__(64) void k_alpha0(const int* __restrict__ rowstart,
    const int* __restrict__ csr, const float* __restrict__ a_s0,
    const float* __restrict__ a_d0,
    float* __restrict__ alb8, float* __restrict__ id0) {
    const int i = blockIdx.x;
    const int t = threadIdx.x;
    const int slot = t >> 3, h = t & 7;
    const int jb = rowstart[i], je = rowstart[i + 1];
    const float ad = a_d0[i * 8 + h];
    float mx = -3.4e38f;
    for (int j = jb + slot; j < je; j += 8) {
        int s = csr[j];
        float e = a_s0[s * 8 + h] + ad;
        e = (e > 0.f) ? e : NEG_SLOPE * e;
        alb8[j * 8 + h] = e;
        mx = fmaxf(mx, e);
    }
    mx = fmaxf(mx, __shfl_xor(mx, 8));
    mx = fmaxf(mx, __shfl_xor(mx, 16));
    mx = fmaxf(mx, __shfl_xor(mx, 32));
    float sum = 0.f;
    for (int j = jb + slot; j < je; j += 8) {
        float e = alb8[j * 8 + h];
        float p = __expf(e - mx);
        alb8[j * 8 + h] = p;
        sum += p;
    }
    sum += __shfl_xor(sum, 8);
    sum += __shfl_xor(sum, 16);
    sum += __shfl_xor(sum, 32);
    if (t < 8) id0[i * 8 + t] = 1.f / (sum + 1e-16f);
}

// -------- layer0 aggregation: one wave per node, lane l covers feats 4l..4l+3 --------
__global__ __launch_bounds__(256) void k_agg0(const int* __restrict__ rowstart,
    const int* __restrict__ csr, const float* __restrict__ alb8,
    const float* __restrict__ id0, const float* __restrict__ hW0,
    const float* __restrict__ bg0, const float* __restrict__ g0,
    const float* __restrict__ b0, float* __restrict__ resio) {
    const int t = threadIdx.x;
    const int w = t >> 6, l = t & 63;
    const int i = blockIdx.x * 4 + w;
    const int h = l >> 3;
    const int jb = rowstart[i], je = rowstart[i + 1];
    float4 acc = make_float4(0.f, 0.f, 0.f, 0.f);
    int j = jb;
    for (; j + 1 < je; j += 2) {
        int s0 = csr[j], s1 = csr[j + 1];
        float p0 = alb8[j * 8 + h], p1 = alb8[(j + 1) * 8 + h];
        float4 v0 = *(const float4*)(hW0 + s0 * 256 + l * 4);
        float4 v1 = *(const float4*)(hW0 + s1 * 256 + l * 4);
        acc.x = fmaf(p0, v0.x, acc.x); acc.y = fmaf(p0, v0.y, acc.y);
        acc.z = fmaf(p0, v0.z, acc.z); acc.w = fmaf(p0, v0.w, acc.w);
        acc.x = fmaf(p1, v1.x, acc.x); acc.y = fmaf(p1, v1.y, acc.y);
        acc.z = fmaf(p1, v1.z, acc.z); acc.w = fmaf(p1, v1.w, acc.w);
    }
    if (j < je) {
        int s0 = csr[j];
        float p0 = alb8[j * 8 + h];
        float4 v0 = *(const float4*)(hW0 + s0 * 256 + l * 4);
        acc.x = fmaf(p0, v0.x, acc.x); acc.y = fmaf(p0, v0.y, acc.y);
        acc.z = fmaf(p0, v0.z, acc.z); acc.w = fmaf(p0, v0.w, acc.w);
    }
    const float inv = id0[i * 8 + h];
    float4 bg = *(const float4*)(bg0 + l * 4);
    float4 val;
    val.x = fmaf(acc.x, inv, bg.x); val.y = fmaf(acc.y, inv, bg.y);
    val.z = fmaf(acc.z, inv, bg.z); val.w = fmaf(acc.w, inv, bg.w);
    val.x = (val.x > 0.f) ? val.x : expm1f(val.x);
    val.y = (val.y > 0.f) ? val.y : expm1f(val.y);
    val.z = (val.z > 0.f) ? val.z : expm1f(val.z);
    val.w = (val.w > 0.f) ? val.w : expm1f(val.w);
    float4 rs = *(const float4*)(resio + i * 256 + l * 4);
    val.x += rs.x; val.y += rs.y; val.z += rs.z; val.w += rs.w;
    // LayerNorm over 256 (wave-local)
    float sm = val.x + val.y + val.z + val.w;
#pragma unroll
    for (int o = 32; o >= 1; o >>= 1) sm += __shfl_xor(sm, o);
    float mean = sm * (1.f / 256.f);
    float4 d;
    d.x = val.x - mean; d.y = val.y - mean; d.z = val.z - mean; d.w = val.w - mean;
    float vv = d.x * d.x + d.y * d.y + d.z * d.z + d.w * d.w;
#pragma unroll
    for (int o = 32; o >= 1; o >>= 1) vv += __shfl_xor(vv, o);
    float rstd = rsqrtf(vv * (1.f / 256.f) + LN_EPS);
    float4 gv = *(const float4*)(g0 + l * 4);
    float4 bv = *(const float4*)(b0 + l * 4);
    float4 outv;
    outv.x = fmaf(d.x * rstd, gv.x, bv.x); outv.y = fmaf(d.y * rstd, gv.y, bv.y);
    outv.z = fmaf(d.z * rstd, gv.z, bv.z); outv.w = fmaf(d.w * rstd, gv.w, bv.w);
    *(float4*)(resio + i * 256 + l * 4) = outv;
}

// ------------- layer1 linears: kc=t&7 (K-chunk), col=t>>3; shuffle-reduced -------------
__global__ __launch_bounds__(256) void k_lin1(const float* __restrict__ h1,
    const float* __restrict__ Wr1, const float* __restrict__ br1,
    const float* __restrict__ W1,
    float* __restrict__ res1, float* __restrict__ hW1) {
    const int t = threadIdx.x;
    const int kc = t & 7, col = t >> 3;
    float wr[32], wc[32];
#pragma unroll
    for (int j = 0; j < 32; j++) {
        wr[j] = Wr1[(kc * 32 + j) * 32 + col];
        wc[j] = W1[(kc * 32 + j) * 32 + col];
    }
    const float brv = br1[col];
    __shared__ float sh[8 * 288];      // 8 nodes x (8 chunks * 36 padded)
    const int blockBase = blockIdx.x * 64;
    for (int g = 0; g < 8; g++) {
        const int nb = blockBase + g * 8;
        __syncthreads();
#pragma unroll
        for (int r = 0; r < 8; r++) {
            int node = nb + r;
            sh[r * 288 + (t >> 5) * 36 + (t & 31)] =
                (node < N_NODES) ? h1[node * 256 + t] : 0.f;
        }
        __syncthreads();
        for (int r = 0; r < 8; r++) {
            int node = nb + r;
            if (node >= N_NODES) break;
            const float4* lp = (const float4*)(sh + r * 288 + kc * 36);
            float sr = 0.f, sw = 0.f;
#pragma unroll
            for (int q = 0; q < 8; q++) {
                float4 v = lp[q];
                sr = fmaf(v.x, wr[4*q+0], sr); sw = fmaf(v.x, wc[4*q+0], sw);
                sr = fmaf(v.y, wr[4*q+1], sr); sw = fmaf(v.y, wc[4*q+1], sw);
                sr = fmaf(v.z, wr[4*q+2], sr); sw = fmaf(v.z, wc[4*q+2], sw);
                sr = fmaf(v.w, wr[4*q+3], sr); sw = fmaf(v.w, wc[4*q+3], sw);
            }
            sr += __shfl_xor(sr, 1); sw += __shfl_xor(sw, 1);
            sr += __shfl_xor(sr, 2); sw += __shfl_xor(sw, 2);
            sr += __shfl_xor(sr, 4); sw += __shfl_xor(sw, 4);
            if (kc == 0) {
                res1[node * 32 + col] = sr + brv;
                hW1[node * 32 + col] = sw;
            }
        }
    }
}

// ------------- layer1 attention dots from hW1 -------------
__global__ __launch_bounds__(256) void k_att1(const float* __restrict__ hW1,
    const float* __restrict__ as1, const float* __restrict__ ad1,
    float* __restrict__ a_s1, float* __restrict__ a_d1) {
    const int idx = blockIdx.x * 256 + threadIdx.x;
    const int i = idx >> 5, f = idx & 31;
    float w = hW1[idx];
    float ps = w * as1[f], pd = w * ad1[f];
#pragma unroll
    for (int o = 16; o >= 1; o >>= 1) { ps += __shfl_xor(ps, o); pd += __shfl_xor(pd, o); }
    if (f == 0) { a_s1[i] = ps; a_d1[i] = pd; }
}

// -------- layer1 softmax weights: one wave per node --------
__global__ __launch_bounds__(64) void k_alpha1(const int* __restrict__ rowstart,
    const int* __restrict__ csr, const float* __restrict__ a_s1,
    const float* __restrict__ a_d1,
    float* __restrict__ alb1, float* __restrict__ id1) {
    const int i = blockIdx.x;
    const int t = threadIdx.x;
    const int jb = rowstart[i], je = rowstart[i + 1];
    const float ad = a_d1[i];
    float mx = -3.4e38f;
    for (int j = jb + t; j < je; j += 64) {
        int s = csr[j];
        float e = a_s1[s] + ad;
        e = (e > 0.f) ? e : NEG_SLOPE * e;
        alb1[j] = e;
        mx = fmaxf(mx, e);
    }
#pragma unroll
    for (int o = 32; o >= 1; o >>= 1) mx = fmaxf(mx, __shfl_xor(mx, o));
    float sum = 0.f;
    for (int j = jb + t; j < je; j += 64) {
        float p = __expf(alb1[j] - mx);
        alb1[j] = p;
        sum += p;
    }
#pragma unroll
    for (int o = 32; o >= 1; o >>= 1) sum += __shfl_xor(sum, o);
    if (t == 0) id1[i] = 1.f / (sum + 1e-16f);
}

// -------- layer1 aggregation: 8 lanes per node (feats as float4) + LN --------
__global__ __launch_bounds__(256) void k_agg1(const int* __restrict__ rowstart,
    const int* __restrict__ csr, const float* __restrict__ alb1,
    const float* __restrict__ id1, const float* __restrict__ hW1,
    const float* __restrict__ bg1, const float* __restrict__ res1,
    const float* __restrict__ g1, const float* __restrict__ b1,
    float* __restrict__ h2) {
    const int t = threadIdx.x;
    const int i = blockIdx.x * 32 + (t >> 3);
    const int u = t & 7;
    if (i >= N_NODES) return;
    const int jb = rowstart[i], je = rowstart[i + 1];
    float4 acc = make_float4(0.f, 0.f, 0.f, 0.f);
    for (int j = jb; j < je; j++) {
        int s = csr[j];
        float p = alb1[j];
        float4 v = *(const float4*)(hW1 + s * 32 + u * 4);
        acc.x = fmaf(p, v.x, acc.x); acc.y = fmaf(p, v.y, acc.y);
        acc.z = fmaf(p, v.z, acc.z); acc.w = fmaf(p, v.w, acc.w);
    }
    const float inv = id1[i];
    float4 bg = *(const float4*)(bg1 + u * 4);
    float4 rs = *(const float4*)(res1 + i * 32 + u * 4);
    float4 val;
    val.x = fmaf(acc.x, inv, bg.x) + rs.x; val.y = fmaf(acc.y, inv, bg.y) + rs.y;
    val.z = fmaf(acc.z, inv, bg.z) + rs.z; val.w = fmaf(acc.w, inv, bg.w) + rs.w;
    float sm = val.x + val.y + val.z + val.w;
    sm += __shfl_xor(sm, 1); sm += __shfl_xor(sm, 2); sm += __shfl_xor(sm, 4);
    float mean = sm * (1.f / 32.f);
    float4 d;
    d.x = val.x - mean; d.y = val.y - mean; d.z = val.z - mean; d.w = val.w - mean;
    float vv = d.x * d.x + d.y * d.y + d.z * d.z + d.w * d.w;
    vv += __shfl_xor(vv, 1); vv += __shfl_xor(vv, 2); vv += __shfl_xor(vv, 4);
    float rstd = rsqrtf(vv * (1.f / 32.f) + LN_EPS);
    float4 gv = *(const float4*)(g1 + u * 4);
    float4 bv = *(const float4*)(b1 + u * 4);
    float4 outv;
    outv.x = fmaf(d.x * rstd, gv.x, bv.x); outv.y = fmaf(d.y * rstd, gv.y, bv.y);
    outv.z = fmaf(d.z * rstd, gv.z, bv.z); outv.w = fmaf(d.w * rstd, gv.w, bv.w);
    *(float4*)(h2 + i * 32 + u * 4) = outv;
}

// ---------------- global mean pool partials ----------------
__global__ __launch_bounds__(256) void k_pool(const float* __restrict__ h2, float* __restrict__ partial) {
    const int t = threadIdx.x;
    const int col = t & 31, sub = t >> 5;
    float acc = 0.f;
    for (int i = blockIdx.x * 8 + sub; i < N_NODES; i += 64 * 8) acc += h2[i * 32 + col];
    __shared__ float s[256];
    s[t] = acc; __syncthreads();
    if (t < 32) {
        float a = 0.f;
        for (int k = 0; k < 8; k++) a += s[k * 32 + t];
        partial[blockIdx.x * 32 + t] = a;
    }
}

// ---------------- final: pooled @ Wout + bout ----------------
__global__ __launch_bounds__(64) void k_final(const float* __restrict__ partial,
                                              const float* __restrict__ Wout,
                                              const float* __restrict__ bout,
                                              float* __restrict__ out) {
    __shared__ float pooled[32];
    int t = threadIdx.x;
    if (t < 32) {
        float a = 0.f;
        for (int b = 0; b < 64; b++) a += partial[b * 32 + t];
        pooled[t] = a * (1.f / (float)N_NODES);
    }
    __syncthreads();
    if (t < OUTD) {
        float o = bout[t];
        for (int c = 0; c < 32; c++) o = fmaf(pooled[c], Wout[c * OUTD + t], o);
        out[t] = o;
    }
}

extern "C" void kernel_launch(void* const* d_in, const int* in_sizes, int n_in,
                              void* d_out, int out_size, void* d_ws, size_t ws_size,
                              hipStream_t stream) {
    const float* x    = (const float*)d_in[0];
    const int*   eidx = (const int*)d_in[1];      // [0,E)=src, [E,2E)=dst
    const float* Win  = (const float*)d_in[3];
    const float* bin  = (const float*)d_in[4];
    const float* Wr0  = (const float*)d_in[5];
    const float* br0  = (const float*)d_in[6];
    const float* W0   = (const float*)d_in[7];
    const float* as0  = (const float*)d_in[8];
    const float* ad0  = (const float*)d_in[9];
    const float* bg0  = (const float*)d_in[10];
    const float* g0   = (const float*)d_in[11];
    const float* b0   = (const float*)d_in[12];
    const float* Wr1  = (const float*)d_in[13];
    const float* br1  = (const float*)d_in[14];
    const float* W1   = (const float*)d_in[15];
    const float* as1  = (const float*)d_in[16];
    const float* ad1  = (const float*)d_in[17];
    const float* bg1  = (const float*)d_in[18];
    const float* g1   = (const float*)d_in[19];
    const float* b1   = (const float*)d_in[20];
    const float* Wout = (const float*)d_in[21];
    const float* bout = (const float*)d_in[22];
    float* out = (float*)d_out;

    const int* srcA = eidx;
    const int* dstA = eidx + N_EDGES;

    // workspace layout (floats)
    float* ws = (float*)d_ws;
    float* res0 = ws;                          // N*256 (becomes h1 in-place)
    float* hW0  = ws + 12800000;               // N*256
    float* a_s0 = ws + 25600000;               // N*8
    float* a_d0 = ws + 26000000;               // N*8
    float* id0  = ws + 26400000;               // N*8
    float* alb8 = ws + 26800000;               // (E+N)*8 = 6.8M  [dead after k_agg0]
    // layer-1 temps overlay alb8's region (all used strictly after k_agg0)
    float* res1 = alb8;                        // N*32
    float* hW1  = alb8 + 1600000;              // N*32
    float* a_s1 = alb8 + 3200000;              // N
    float* a_d1 = alb8 + 3250000;              // N
    float* id1  = alb8 + 3300000;              // N
    float* alb1 = alb8 + 3350000;              // E+N
    float* h2   = alb8 + 4200000;              // N*32
    float* partial = alb8 + 5800000;           // 64*32
    int* ib = (int*)(ws + 33600000);
    int* rowstart = ib;                        // N+1
    int* cursor   = rowstart + N_NODES + 1;    // N
    int* bsum     = cursor + N_NODES;          // NB0
    int* boff     = bsum + NB0;                // NB0
    int* csr      = boff + NB0;                // E+N
    int* deg      = csr + (N_EDGES + N_NODES); // N

    // dense front (h0 computed on the fly)
    k_lin0<<<(N_NODES + 31) / 32, 256, 0, stream>>>(x, Win, bin, Wr0, br0, W0, as0, ad0,
                                                    res0, hW0, a_s0, a_d0);
    // CSR build
    k_deg_init<<<NB0, 256, 0, stream>>>(deg);
    k_deg_count<<<(N_EDGES + 255) / 256, 256, 0, stream>>>(dstA, deg);
    k_scan1<<<NB0, 256, 0, stream>>>(deg, rowstart, bsum);
    k_scan2<<<1, 256, 0, stream>>>(bsum, rowstart, boff);
    k_scan3<<<NB0, 256, 0, stream>>>(rowstart, boff, cursor);
    k_scatter<<<(N_EDGES + 255) / 256, 256, 0, stream>>>(srcA, dstA, cursor, csr);
    k_scatter_loops<<<NB0, 256, 0, stream>>>(cursor, csr);
    // layer 0: softmax weights then gather-aggregate (+ELU+residual+LN), h1 over res0
    k_alpha0<<<N_NODES, 64, 0, stream>>>(rowstart, csr, a_s0, a_d0, alb8, id0);
    k_agg0<<<N_NODES / 4, 256, 0, stream>>>(rowstart, csr, alb8, id0, hW0, bg0, g0, b0, res0);
    // layer 1
    k_lin1<<<(N_NODES + 63) / 64, 256, 0, stream>>>(res0, Wr1, br1, W1, res1, hW1);
    k_att1<<<(N_NODES * 32) / 256, 256, 0, stream>>>(hW1, as1, ad1, a_s1, a_d1);
    k_alpha1<<<N_NODES, 64, 0, stream>>>(rowstart, csr, a_s1, a_d1, alb1, id1);
    k_agg1<<<(N_NODES + 31) / 32, 256, 0, stream>>>(rowstart, csr, alb1, id1, hW1,
                                                    bg1, res1, g1, b1, h2);
    // pool + head
    k_pool<<<64, 256, 0, stream>>>(h2, partial);
    k_final<<<1, 64, 0, stream>>>(partial, Wout, bout, out);
}

// Round 3
// 493.712 us; speedup vs baseline: 1.3205x; 1.0791x over previous
//
#include <hip/hip_runtime.h>
#include <hip/hip_fp16.h>
#include <math.h>

#define N_NODES 50000
#define N_EDGES 800000
#define HEADS 8
#define OUTD 16
#define NEG_SLOPE 0.2f
#define LN_EPS 1e-5f
#define NB0 196           // ceil(N/256)

// ------------- layer0: h0 = x*Win+bin on the fly; res0 = h0@Wr0+br0 (fp32),
// hW0 = h0@W0 (fp16 store), attention dots. 256 thr = one output col, 64 nodes/block.
__global__ __launch_bounds__(256) void k_lin0(const float* __restrict__ x,
    const float* __restrict__ Win, const float* __restrict__ bin,
    const float* __restrict__ Wr0, const float* __restrict__ br0,
    const float* __restrict__ W0,  const float* __restrict__ as0,
    const float* __restrict__ ad0,
    float* __restrict__ res0, __half* __restrict__ hW0h,
    float* __restrict__ a_s0, float* __restrict__ a_d0) {
    const int t = threadIdx.x;
    const int base = blockIdx.x * 64;
    __shared__ float sx[64];
    __shared__ float lh[64 * 32];
    float wr[32], wc[32];
#pragma unroll
    for (int k = 0; k < 32; k++) { wr[k] = Wr0[k * 256 + t]; wc[k] = W0[k * 256 + t]; }
    const float brv = br0[t], asv = as0[t], adv = ad0[t];
    if (t < 64) sx[t] = (base + t < N_NODES) ? x[base + t] : 0.f;
    __syncthreads();
    const float winv = Win[t & 31], binv = bin[t & 31];
    for (int idx = t; idx < 2048; idx += 256) {
        int m = idx >> 5;
        lh[idx] = fmaf(sx[m], winv, binv);
    }
    __syncthreads();
    int mmax = min(64, N_NODES - base);
    for (int m = 0; m < mmax; m++) {
        int node = base + m;
        const float4* lp = (const float4*)(lh + m * 32);
        float ar = brv, aw = 0.f;
#pragma unroll
        for (int q = 0; q < 8; q++) {
            float4 v = lp[q];
            ar = fmaf(v.x, wr[4*q+0], ar); aw = fmaf(v.x, wc[4*q+0], aw);
            ar = fmaf(v.y, wr[4*q+1], ar); aw = fmaf(v.y, wc[4*q+1], aw);
            ar = fmaf(v.z, wr[4*q+2], ar); aw = fmaf(v.z, wc[4*q+2], aw);
            ar = fmaf(v.w, wr[4*q+3], ar); aw = fmaf(v.w, wc[4*q+3], aw);
        }
        res0[node * 256 + t] = ar;
        hW0h[(size_t)node * 256 + t] = __float2half(aw);
        float ps = aw * asv, pd = aw * adv;
#pragma unroll
        for (int o = 16; o >= 1; o >>= 1) { ps += __shfl_xor(ps, o); pd += __shfl_xor(pd, o); }
        if ((t & 31) == 0) { a_s0[node * 8 + (t >> 5)] = ps; a_d0[node * 8 + (t >> 5)] = pd; }
    }
}

// ---------------- CSR build by dst ----------------
__global__ __launch_bounds__(256) void k_deg_init(int* deg) {
    int i = blockIdx.x * 256 + threadIdx.x;
    if (i < N_NODES) deg[i] = 1;   // self-loop
}
__global__ __launch_bounds__(256) void k_deg_count(const int* __restrict__ dstA, int* deg) {
    int e = blockIdx.x * 256 + threadIdx.x;
    if (e < N_EDGES) atomicAdd(&deg[dstA[e]], 1);
}
__global__ __launch_bounds__(256) void k_scan1(const int* __restrict__ deg,
                                               int* __restrict__ rowstart, int* __restrict__ bsum) {
    __shared__ int s[256];
    int t = threadIdx.x;
    int i = blockIdx.x * 256 + t;
    int v = (i < N_NODES) ? deg[i] : 0;
    s[t] = v; __syncthreads();
    for (int o = 1; o < 256; o <<= 1) {
        int xv = (t >= o) ? s[t - o] : 0;
        __syncthreads();
        s[t] += xv;
        __syncthreads();
    }
    if (i < N_NODES) rowstart[i] = s[t] - v;
    if (t == 255) bsum[blockIdx.x] = s[255];
}
__global__ __launch_bounds__(256) void k_scan2(const int* __restrict__ bsum,
                                               int* __restrict__ rowstart, int* __restrict__ boff) {
    __shared__ int s[256];
    int t = threadIdx.x;
    int v = (t < NB0) ? bsum[t] : 0;
    s[t] = v; __syncthreads();
    for (int o = 1; o < 256; o <<= 1) {
        int xv = (t >= o) ? s[t - o] : 0;
        __syncthreads();
        s[t] += xv;
        __syncthreads();
    }
    if (t < NB0) boff[t] = s[t] - v;
    if (t == 255) rowstart[N_NODES] = s[255];   // = E + N
}
__global__ __launch_bounds__(256) void k_scan3(int* __restrict__ rowstart,
                                               const int* __restrict__ boff, int* __restrict__ cursor) {
    int t = threadIdx.x;
    int i = blockIdx.x * 256 + t;
    if (i < N_NODES) {
        int r = rowstart[i] + boff[blockIdx.x];
        rowstart[i] = r;
        cursor[i] = r;
    }
}
__global__ __launch_bounds__(256) void k_scatter(const int* __restrict__ srcA,
                                                 const int* __restrict__ dstA,
                                                 int* cursor, int* __restrict__ csr) {
    int e = blockIdx.x * 256 + threadIdx.x;
    if (e < N_EDGES) {
        int d = dstA[e];
        int p = atomicAdd(&cursor[d], 1);
        csr[p] = srcA[e];
    }
    if (e < N_NODES) {
        int p = atomicAdd(&cursor[e], 1);
        csr[p] = e;
    }
}

// -------- layer0 softmax weights: one wave per node (4 nodes/block) --------
__global__ __launch_bounds__(256) void k_alpha0(const int* __restrict__ rowstart,
    const int* __restrict__ csr, const float* __restrict__ a_s0,
    const float* __restrict__ a_d0,
    float* __restrict__ alb8, float* __restrict__ id0) {
    const int t = threadIdx.x;
    const int i = blockIdx.x * 4 + (t >> 6);
    const int l = t & 63;
    const int slot = l >> 3, h = l & 7;
    const int jb = rowstart[i], je = rowstart[i + 1];
    const float ad = a_d0[i * 8 + h];
    float mx = -3.4e38f;
    for (int j = jb + slot; j < je; j += 8) {
        int s = csr[j];
        float e = a_s0[s * 8 + h] + ad;
        e = (e > 0.f) ? e : NEG_SLOPE * e;
        alb8[j * 8 + h] = e;
        mx = fmaxf(mx, e);
    }
    mx = fmaxf(mx, __shfl_xor(mx, 8));
    mx = fmaxf(mx, __shfl_xor(mx, 16));
    mx = fmaxf(mx, __shfl_xor(mx, 32));
    float sum = 0.f;
    for (int j = jb + slot; j < je; j += 8) {
        float e = alb8[j * 8 + h];
        float p = __expf(e - mx);
        alb8[j * 8 + h] = p;
        sum += p;
    }
    sum += __shfl_xor(sum, 8);
    sum += __shfl_xor(sum, 16);
    sum += __shfl_xor(sum, 32);
    if (l < 8) id0[i * 8 + l] = 1.f / (sum + 1e-16f);
}

// -------- layer0 aggregation (fp16 gather): one wave per node --------
__global__ __launch_bounds__(256) void k_agg0(const int* __restrict__ rowstart,
    const int* __restrict__ csr, const float* __restrict__ alb8,
    const float* __restrict__ id0, const __half* __restrict__ hW0h,
    const float* __restrict__ bg0, const float* __restrict__ g0,
    const float* __restrict__ b0, float* __restrict__ resio) {
    const int t = threadIdx.x;
    const int w = t >> 6, l = t & 63;
    const int i = blockIdx.x * 4 + w;
    const int h = l >> 3;
    const int jb = rowstart[i], je = rowstart[i + 1];
    float4 acc = make_float4(0.f, 0.f, 0.f, 0.f);
    int j = jb;
    for (; j + 1 < je; j += 2) {
        int s0 = csr[j], s1 = csr[j + 1];
        float p0 = alb8[j * 8 + h], p1 = alb8[(j + 1) * 8 + h];
        uint2 u0 = *(const uint2*)(hW0h + (size_t)s0 * 256 + l * 4);
        uint2 u1 = *(const uint2*)(hW0h + (size_t)s1 * 256 + l * 4);
        float2 a0 = __half22float2(*(const __half2*)&u0.x);
        float2 a1 = __half22float2(*(const __half2*)&u0.y);
        float2 c0 = __half22float2(*(const __half2*)&u1.x);
        float2 c1 = __half22float2(*(const __half2*)&u1.y);
        acc.x = fmaf(p0, a0.x, acc.x); acc.y = fmaf(p0, a0.y, acc.y);
        acc.z = fmaf(p0, a1.x, acc.z); acc.w = fmaf(p0, a1.y, acc.w);
        acc.x = fmaf(p1, c0.x, acc.x); acc.y = fmaf(p1, c0.y, acc.y);
        acc.z = fmaf(p1, c1.x, acc.z); acc.w = fmaf(p1, c1.y, acc.w);
    }
    if (j < je) {
        int s0 = csr[j];
        float p0 = alb8[j * 8 + h];
        uint2 u0 = *(const uint2*)(hW0h + (size_t)s0 * 256 + l * 4);
        float2 a0 = __half22float2(*(const __half2*)&u0.x);
        float2 a1 = __half22float2(*(const __half2*)&u0.y);
        acc.x = fmaf(p0, a0.x, acc.x); acc.y = fmaf(p0, a0.y, acc.y);
        acc.z = fmaf(p0, a1.x, acc.z); acc.w = fmaf(p0, a1.y, acc.w);
    }
    const float inv = id0[i * 8 + h];
    float4 bg = *(const float4*)(bg0 + l * 4);
    float4 val;
    val.x = fmaf(acc.x, inv, bg.x); val.y = fmaf(acc.y, inv, bg.y);
    val.z = fmaf(acc.z, inv, bg.z); val.w = fmaf(acc.w, inv, bg.w);
    val.x = (val.x > 0.f) ? val.x : expm1f(val.x);
    val.y = (val.y > 0.f) ? val.y : expm1f(val.y);
    val.z = (val.z > 0.f) ? val.z : expm1f(val.z);
    val.w = (val.w > 0.f) ? val.w : expm1f(val.w);
    float4 rs = *(const float4*)(resio + (size_t)i * 256 + l * 4);
    val.x += rs.x; val.y += rs.y; val.z += rs.z; val.w += rs.w;
    float sm = val.x + val.y + val.z + val.w;
#pragma unroll
    for (int o = 32; o >= 1; o >>= 1) sm += __shfl_xor(sm, o);
    float mean = sm * (1.f / 256.f);
    float4 d;
    d.x = val.x - mean; d.y = val.y - mean; d.z = val.z - mean; d.w = val.w - mean;
    float vv = d.x * d.x + d.y * d.y + d.z * d.z + d.w * d.w;
#pragma unroll
    for (int o = 32; o >= 1; o >>= 1) vv += __shfl_xor(vv, o);
    float rstd = rsqrtf(vv * (1.f / 256.f) + LN_EPS);
    float4 gv = *(const float4*)(g0 + l * 4);
    float4 bv = *(const float4*)(b0 + l * 4);
    float4 outv;
    outv.x = fmaf(d.x * rstd, gv.x, bv.x); outv.y = fmaf(d.y * rstd, gv.y, bv.y);
    outv.z = fmaf(d.z * rstd, gv.z, bv.z); outv.w = fmaf(d.w * rstd, gv.w, bv.w);
    *(float4*)(resio + (size_t)i * 256 + l * 4) = outv;
}

// ------------- layer1 linears: kc=t&7 (K-chunk), col=t>>3; shuffle-reduced -------------
__global__ __launch_bounds__(256) void k_lin1(const float* __restrict__ h1,
    const float* __restrict__ Wr1, const float* __restrict__ br1,
    const float* __restrict__ W1,
    float* __restrict__ res1, __half* __restrict__ hW1h) {
    const int t = threadIdx.x;
    const int kc = t & 7, col = t >> 3;
    float wr[32], wc[32];
#pragma unroll
    for (int j = 0; j < 32; j++) {
        wr[j] = Wr1[(kc * 32 + j) * 32 + col];
        wc[j] = W1[(kc * 32 + j) * 32 + col];
    }
    const float brv = br1[col];
    __shared__ float sh[8 * 288];      // 8 nodes x (8 chunks * 36 padded)
    const int blockBase = blockIdx.x * 64;
    for (int g = 0; g < 8; g++) {
        const int nb = blockBase + g * 8;
        __syncthreads();
#pragma unroll
        for (int r = 0; r < 8; r++) {
            int node = nb + r;
            sh[r * 288 + (t >> 5) * 36 + (t & 31)] =
                (node < N_NODES) ? h1[(size_t)node * 256 + t] : 0.f;
        }
        __syncthreads();
        for (int r = 0; r < 8; r++) {
            int node = nb + r;
            if (node >= N_NODES) break;
            const float4* lp = (const float4*)(sh + r * 288 + kc * 36);
            float sr = 0.f, sw = 0.f;
#pragma unroll
            for (int q = 0; q < 8; q++) {
                float4 v = lp[q];
                sr = fmaf(v.x, wr[4*q+0], sr); sw = fmaf(v.x, wc[4*q+0], sw);
                sr = fmaf(v.y, wr[4*q+1], sr); sw = fmaf(v.y, wc[4*q+1], sw);
                sr = fmaf(v.z, wr[4*q+2], sr); sw = fmaf(v.z, wc[4*q+2], sw);
                sr = fmaf(v.w, wr[4*q+3], sr); sw = fmaf(v.w, wc[4*q+3], sw);
            }
            sr += __shfl_xor(sr, 1); sw += __shfl_xor(sw, 1);
            sr += __shfl_xor(sr, 2); sw += __shfl_xor(sw, 2);
            sr += __shfl_xor(sr, 4); sw += __shfl_xor(sw, 4);
            if (kc == 0) {
                res1[node * 32 + col] = sr + brv;
                hW1h[node * 32 + col] = __float2half(sw);
            }
        }
    }
}

// ------------- layer1 attention dots from hW1 (fp16) -------------
__global__ __launch_bounds__(256) void k_att1(const __half* __restrict__ hW1h,
    const float* __restrict__ as1, const float* __restrict__ ad1,
    float* __restrict__ a_s1, float* __restrict__ a_d1) {
    const int idx = blockIdx.x * 256 + threadIdx.x;
    const int i = idx >> 5, f = idx & 31;
    float w = __half2float(hW1h[idx]);
    float ps = w * as1[f], pd = w * ad1[f];
#pragma unroll
    for (int o = 16; o >= 1; o >>= 1) { ps += __shfl_xor(ps, o); pd += __shfl_xor(pd, o); }
    if (f == 0) { a_s1[i] = ps; a_d1[i] = pd; }
}

// -------- layer1 softmax weights: one wave per node (4 nodes/block) --------
__global__ __launch_bounds__(256) void k_alpha1(const int* __restrict__ rowstart,
    const int* __restrict__ csr, const float* __restrict__ a_s1,
    const float* __restrict__ a_d1,
    float* __restrict__ alb1, float* __restrict__ id1) {
    const int t = threadIdx.x;
    const int i = blockIdx.x * 4 + (t >> 6);
    const int l = t & 63;
    const int jb = rowstart[i], je = rowstart[i + 1];
    const float ad = a_d1[i];
    float mx = -3.4e38f;
    for (int j = jb + l; j < je; j += 64) {
        int s = csr[j];
        float e = a_s1[s] + ad;
        e = (e > 0.f) ? e : NEG_SLOPE * e;
        alb1[j] = e;
        mx = fmaxf(mx, e);
    }
#pragma unroll
    for (int o = 32; o >= 1; o >>= 1) mx = fmaxf(mx, __shfl_xor(mx, o));
    float sum = 0.f;
    for (int j = jb + l; j < je; j += 64) {
        float p = __expf(alb1[j] - mx);
        alb1[j] = p;
        sum += p;
    }
#pragma unroll
    for (int o = 32; o >= 1; o >>= 1) sum += __shfl_xor(sum, o);
    if (l == 0) id1[i] = 1.f / (sum + 1e-16f);
}

// -------- layer1 aggregation (fp16 gather): 8 lanes per node + LN --------
__global__ __launch_bounds__(256) void k_agg1(const int* __restrict__ rowstart,
    const int* __restrict__ csr, const float* __restrict__ alb1,
    const float* __restrict__ id1, const __half* __restrict__ hW1h,
    const float* __restrict__ bg1, const float* __restrict__ res1,
    const float* __restrict__ g1, const float* __restrict__ b1,
    float* __restrict__ h2) {
    const int t = threadIdx.x;
    const int i = blockIdx.x * 32 + (t >> 3);
    const int u = t & 7;
    if (i >= N_NODES) return;
    const int jb = rowstart[i], je = rowstart[i + 1];
    float4 acc = make_float4(0.f, 0.f, 0.f, 0.f);
    for (int j = jb; j < je; j++) {
        int s = csr[j];
        float p = alb1[j];
        uint2 uu = *(const uint2*)(hW1h + s * 32 + u * 4);
        float2 v0 = __half22float2(*(const __half2*)&uu.x);
        float2 v1 = __half22float2(*(const __half2*)&uu.y);
        acc.x = fmaf(p, v0.x, acc.x); acc.y = fmaf(p, v0.y, acc.y);
        acc.z = fmaf(p, v1.x, acc.z); acc.w = fmaf(p, v1.y, acc.w);
    }
    const float inv = id1[i];
    float4 bg = *(const float4*)(bg1 + u * 4);
    float4 rs = *(const float4*)(res1 + i * 32 + u * 4);
    float4 val;
    val.x = fmaf(acc.x, inv, bg.x) + rs.x; val.y = fmaf(acc.y, inv, bg.y) + rs.y;
    val.z = fmaf(acc.z, inv, bg.z) + rs.z; val.w = fmaf(acc.w, inv, bg.w) + rs.w;
    float sm = val.x + val.y + val.z + val.w;
    sm += __shfl_xor(sm, 1); sm += __shfl_xor(sm, 2); sm += __shfl_xor(sm, 4);
    float mean = sm * (1.f / 32.f);
    float4 d;
    d.x = val.x - mean; d.y = val.y - mean; d.z = val.z - mean; d.w = val.w - mean;
    float vv = d.x * d.x + d.y * d.y + d.z * d.z + d.w * d.w;
    vv += __shfl_xor(vv, 1); vv += __shfl_xor(vv, 2); vv += __shfl_xor(vv, 4);
    float rstd = rsqrtf(vv * (1.f / 32.f) + LN_EPS);
    float4 gv = *(const float4*)(g1 + u * 4);
    float4 bv = *(const float4*)(b1 + u * 4);
    float4 outv;
    outv.x = fmaf(d.x * rstd, gv.x, bv.x); outv.y = fmaf(d.y * rstd, gv.y, bv.y);
    outv.z = fmaf(d.z * rstd, gv.z, bv.z); outv.w = fmaf(d.w * rstd, gv.w, bv.w);
    *(float4*)(h2 + i * 32 + u * 4) = outv;
}

// ---------------- global mean pool partials ----------------
__global__ __launch_bounds__(256) void k_pool(const float* __restrict__ h2, float* __restrict__ partial) {
    const int t = threadIdx.x;
    const int col = t & 31, sub = t >> 5;
    float acc = 0.f;
    for (int i = blockIdx.x * 8 + sub; i < N_NODES; i += 64 * 8) acc += h2[i * 32 + col];
    __shared__ float s[256];
    s[t] = acc; __syncthreads();
    if (t < 32) {
        float a = 0.f;
        for (int k = 0; k < 8; k++) a += s[k * 32 + t];
        partial[blockIdx.x * 32 + t] = a;
    }
}

// ---------------- final: pooled @ Wout + bout ----------------
__global__ __launch_bounds__(64) void k_final(const float* __restrict__ partial,
                                              const float* __restrict__ Wout,
                                              const float* __restrict__ bout,
                                              float* __restrict__ out) {
    __shared__ float pooled[32];
    int t = threadIdx.x;
    if (t < 32) {
        float a = 0.f;
        for (int b = 0; b < 64; b++) a += partial[b * 32 + t];
        pooled[t] = a * (1.f / (float)N_NODES);
    }
    __syncthreads();
    if (t < OUTD) {
        float o = bout[t];
        for (int c = 0; c < 32; c++) o = fmaf(pooled[c], Wout[c * OUTD + t], o);
        out[t] = o;
    }
}

extern "C" void kernel_launch(void* const* d_in, const int* in_sizes, int n_in,
                              void* d_out, int out_size, void* d_ws, size_t ws_size,
                              hipStream_t stream) {
    const float* x    = (const float*)d_in[0];
    const int*   eidx = (const int*)d_in[1];      // [0,E)=src, [E,2E)=dst
    const float* Win  = (const float*)d_in[3];
    const float* bin  = (const float*)d_in[4];
    const float* Wr0  = (const float*)d_in[5];
    const float* br0  = (const float*)d_in[6];
    const float* W0   = (const float*)d_in[7];
    const float* as0  = (const float*)d_in[8];
    const float* ad0  = (const float*)d_in[9];
    const float* bg0  = (const float*)d_in[10];
    const float* g0   = (const float*)d_in[11];
    const float* b0   = (const float*)d_in[12];
    const float* Wr1  = (const float*)d_in[13];
    const float* br1  = (const float*)d_in[14];
    const float* W1   = (const float*)d_in[15];
    const float* as1  = (const float*)d_in[16];
    const float* ad1  = (const float*)d_in[17];
    const float* bg1  = (const float*)d_in[18];
    const float* g1   = (const float*)d_in[19];
    const float* b1   = (const float*)d_in[20];
    const float* Wout = (const float*)d_in[21];
    const float* bout = (const float*)d_in[22];
    float* out = (float*)d_out;

    const int* srcA = eidx;
    const int* dstA = eidx + N_EDGES;

    // workspace layout (float offsets)
    float* ws = (float*)d_ws;
    float* res0 = ws;                          // N*256 fp32 (becomes h1 in-place)
    __half* hW0h = (__half*)(ws + 12800000);   // N*256 fp16 = 6.4M floats
    float* a_s0 = ws + 19200000;               // N*8
    float* a_d0 = ws + 19600000;               // N*8
    float* id0  = ws + 20000000;               // N*8
    float* alb8 = ws + 20400000;               // (E+N)*8 = 6.8M  [dead after k_agg0]
    // layer-1 temps overlay alb8's region (all used strictly after k_agg0)
    float* res1 = alb8;                        // N*32
    __half* hW1h = (__half*)(alb8 + 1600000);  // N*32 fp16
    float* a_s1 = alb8 + 2400000;              // N
    float* a_d1 = alb8 + 2450000;              // N
    float* id1  = alb8 + 2500000;              // N
    float* alb1 = alb8 + 2550000;              // E+N
    float* h2   = alb8 + 3400000;              // N*32
    float* partial = alb8 + 5000000;           // 64*32
    int* ib = (int*)(ws + 27200000);
    int* rowstart = ib;                        // N+1
    int* cursor   = rowstart + N_NODES + 1;    // N
    int* bsum     = cursor + N_NODES;          // NB0
    int* boff     = bsum + NB0;                // NB0
    int* csr      = boff + NB0;                // E+N
    int* deg      = csr + (N_EDGES + N_NODES); // N

    // dense front (h0 computed on the fly)
    k_lin0<<<(N_NODES + 63) / 64, 256, 0, stream>>>(x, Win, bin, Wr0, br0, W0, as0, ad0,
                                                    res0, hW0h, a_s0, a_d0);
    // CSR build
    k_deg_init<<<NB0, 256, 0, stream>>>(deg);
    k_deg_count<<<(N_EDGES + 255) / 256, 256, 0, stream>>>(dstA, deg);
    k_scan1<<<NB0, 256, 0, stream>>>(deg, rowstart, bsum);
    k_scan2<<<1, 256, 0, stream>>>(bsum, rowstart, boff);
    k_scan3<<<NB0, 256, 0, stream>>>(rowstart, boff, cursor);
    k_scatter<<<(N_EDGES + 255) / 256, 256, 0, stream>>>(srcA, dstA, cursor, csr);
    // layer 0: softmax weights then gather-aggregate (+ELU+residual+LN), h1 over res0
    k_alpha0<<<N_NODES / 4, 256, 0, stream>>>(rowstart, csr, a_s0, a_d0, alb8, id0);
    k_agg0<<<N_NODES / 4, 256, 0, stream>>>(rowstart, csr, alb8, id0, hW0h, bg0, g0, b0, res0);
    // layer 1
    k_lin1<<<(N_NODES + 63) / 64, 256, 0, stream>>>(res0, Wr1, br1, W1, res1, hW1h);
    k_att1<<<(N_NODES * 32) / 256, 256, 0, stream>>>(hW1h, as1, ad1, a_s1, a_d1);
    k_alpha1<<<N_NODES / 4, 256, 0, stream>>>(rowstart, csr, a_s1, a_d1, alb1, id1);
    k_agg1<<<(N_NODES + 31) / 32, 256, 0, stream>>>(rowstart, csr, alb1, id1, hW1h,
                                                    bg1, res1, g1, b1, h2);
    // pool + head
    k_pool<<<64, 256, 0, stream>>>(h2, partial);
    k_final<<<1, 64, 0, stream>>>(partial, Wout, bout, out);
}

// Round 4
// 467.279 us; speedup vs baseline: 1.3953x; 1.0566x over previous
//
#include <hip/hip_runtime.h>
#include <hip/hip_fp16.h>
#include <math.h>

#define N_NODES 50000
#define N_EDGES 800000
#define HEADS 8
#define OUTD 16
#define NEG_SLOPE 0.2f
#define LN_EPS 1e-5f
#define NB0 196           // ceil(N/256)
#define FP8_SCALE 64.f
#define FP8_INV (1.f / 64.f)

typedef float vf2 __attribute__((ext_vector_type(2)));

// ------------- layer0: h0 = x*Win+bin on the fly; res0 (fp16), hW0 (fp8 x64),
// attention dots. 256 thr = one output col, 64 nodes/block.
__global__ __launch_bounds__(256) void k_lin0(const float* __restrict__ x,
    const float* __restrict__ Win, const float* __restrict__ bin,
    const float* __restrict__ Wr0, const float* __restrict__ br0,
    const float* __restrict__ W0,  const float* __restrict__ as0,
    const float* __restrict__ ad0,
    __half* __restrict__ res0h, unsigned char* __restrict__ hW0q,
    float* __restrict__ a_s0, float* __restrict__ a_d0) {
    const int t = threadIdx.x;
    const int base = blockIdx.x * 64;
    __shared__ float sx[64];
    __shared__ float lh[64 * 32];
    float wr[32], wc[32];
#pragma unroll
    for (int k = 0; k < 32; k++) { wr[k] = Wr0[k * 256 + t]; wc[k] = W0[k * 256 + t]; }
    const float brv = br0[t], asv = as0[t], adv = ad0[t];
    if (t < 64) sx[t] = (base + t < N_NODES) ? x[base + t] : 0.f;
    __syncthreads();
    const float winv = Win[t & 31], binv = bin[t & 31];
    for (int idx = t; idx < 2048; idx += 256) {
        int m = idx >> 5;
        lh[idx] = fmaf(sx[m], winv, binv);
    }
    __syncthreads();
    int mmax = min(64, N_NODES - base);
    for (int m = 0; m < mmax; m++) {
        int node = base + m;
        const float4* lp = (const float4*)(lh + m * 32);
        float ar = brv, aw = 0.f;
#pragma unroll
        for (int q = 0; q < 8; q++) {
            float4 v = lp[q];
            ar = fmaf(v.x, wr[4*q+0], ar); aw = fmaf(v.x, wc[4*q+0], aw);
            ar = fmaf(v.y, wr[4*q+1], ar); aw = fmaf(v.y, wc[4*q+1], aw);
            ar = fmaf(v.z, wr[4*q+2], ar); aw = fmaf(v.z, wc[4*q+2], aw);
            ar = fmaf(v.w, wr[4*q+3], ar); aw = fmaf(v.w, wc[4*q+3], aw);
        }
        res0h[(size_t)node * 256 + t] = __float2half(ar);
        int pk = __builtin_amdgcn_cvt_pk_fp8_f32(aw * FP8_SCALE, 0.f, 0, false);
        hW0q[(size_t)node * 256 + t] = (unsigned char)(pk & 0xff);
        float ps = aw * asv, pd = aw * adv;
#pragma unroll
        for (int o = 16; o >= 1; o >>= 1) { ps += __shfl_xor(ps, o); pd += __shfl_xor(pd, o); }
        if ((t & 31) == 0) { a_s0[node * 8 + (t >> 5)] = ps; a_d0[node * 8 + (t >> 5)] = pd; }
    }
}

// ---------------- CSR build by dst ----------------
__global__ __launch_bounds__(256) void k_deg_count(const int* __restrict__ dstA, int* deg) {
    int e = blockIdx.x * 256 + threadIdx.x;
    if (e < N_EDGES) atomicAdd(&deg[dstA[e]], 1);
}
__global__ __launch_bounds__(256) void k_scan1(const int* __restrict__ deg,
                                               int* __restrict__ rowstart, int* __restrict__ bsum) {
    __shared__ int s[256];
    int t = threadIdx.x;
    int i = blockIdx.x * 256 + t;
    int v = (i < N_NODES) ? (deg[i] + 1) : 0;   // +1 self-loop
    s[t] = v; __syncthreads();
    for (int o = 1; o < 256; o <<= 1) {
        int xv = (t >= o) ? s[t - o] : 0;
        __syncthreads();
        s[t] += xv;
        __syncthreads();
    }
    if (i < N_NODES) rowstart[i] = s[t] - v;
    if (t == 255) bsum[blockIdx.x] = s[255];
}
__global__ __launch_bounds__(256) void k_scan2(const int* __restrict__ bsum,
                                               int* __restrict__ rowstart, int* __restrict__ boff) {
    __shared__ int s[256];
    int t = threadIdx.x;
    int v = (t < NB0) ? bsum[t] : 0;
    s[t] = v; __syncthreads();
    for (int o = 1; o < 256; o <<= 1) {
        int xv = (t >= o) ? s[t - o] : 0;
        __syncthreads();
        s[t] += xv;
        __syncthreads();
    }
    if (t < NB0) boff[t] = s[t] - v;
    if (t == 255) rowstart[N_NODES] = s[255];   // = E + N
}
__global__ __launch_bounds__(256) void k_scan3(int* __restrict__ rowstart,
                                               const int* __restrict__ boff, int* __restrict__ cursor) {
    int t = threadIdx.x;
    int i = blockIdx.x * 256 + t;
    if (i < N_NODES) {
        int r = rowstart[i] + boff[blockIdx.x];
        rowstart[i] = r;
        cursor[i] = r;
    }
}
__global__ __launch_bounds__(256) void k_scatter(const int* __restrict__ srcA,
                                                 const int* __restrict__ dstA,
                                                 int* cursor, int* __restrict__ csr) {
    int e = blockIdx.x * 256 + threadIdx.x;
    if (e < N_EDGES) {
        int d = dstA[e];
        int p = atomicAdd(&cursor[d], 1);
        csr[p] = srcA[e];
    }
    if (e < N_NODES) {
        int p = atomicAdd(&cursor[e], 1);
        csr[p] = e;
    }
}

// -------- layer0 softmax weights (two-pass recompute, fp16 store) --------
// one wave per node (4 nodes/block); slot=l>>3, h=l&7
__global__ __launch_bounds__(256) void k_alpha0(const int* __restrict__ rowstart,
    const int* __restrict__ csr, const float* __restrict__ a_s0,
    const float* __restrict__ a_d0,
    __half* __restrict__ albh, float* __restrict__ id0) {
    const int t = threadIdx.x;
    const int i = blockIdx.x * 4 + (t >> 6);
    const int l = t & 63;
    const int slot = l >> 3, h = l & 7;
    const int jb = rowstart[i], je = rowstart[i + 1];
    const float ad = a_d0[i * 8 + h];
    float mx = -3.4e38f;
    for (int j = jb + slot; j < je; j += 8) {
        int s = csr[j];
        float e = a_s0[s * 8 + h] + ad;
        e = (e > 0.f) ? e : NEG_SLOPE * e;
        mx = fmaxf(mx, e);
    }
    mx = fmaxf(mx, __shfl_xor(mx, 8));
    mx = fmaxf(mx, __shfl_xor(mx, 16));
    mx = fmaxf(mx, __shfl_xor(mx, 32));
    float sum = 0.f;
    for (int j = jb + slot; j < je; j += 8) {
        int s = csr[j];
        float e = a_s0[s * 8 + h] + ad;
        e = (e > 0.f) ? e : NEG_SLOPE * e;
        float p = __expf(e - mx);
        albh[j * 8 + h] = __float2half(p);
        sum += p;
    }
    sum += __shfl_xor(sum, 8);
    sum += __shfl_xor(sum, 16);
    sum += __shfl_xor(sum, 32);
    if (l < 8) id0[i * 8 + l] = 1.f / (sum + 1e-16f);
}

// -------- layer0 aggregation (fp8 gather): one wave per node --------
__global__ __launch_bounds__(256) void k_agg0(const int* __restrict__ rowstart,
    const int* __restrict__ csr, const __half* __restrict__ albh,
    const float* __restrict__ id0, const unsigned char* __restrict__ hW0q,
    const float* __restrict__ bg0, const float* __restrict__ g0,
    const float* __restrict__ b0, __half* __restrict__ resio) {
    const int t = threadIdx.x;
    const int w = t >> 6, l = t & 63;
    const int i = blockIdx.x * 4 + w;
    const int h = l >> 3;
    const int jb = rowstart[i], je = rowstart[i + 1];
    float4 acc = make_float4(0.f, 0.f, 0.f, 0.f);
    int j = jb;
    for (; j + 1 < je; j += 2) {
        int s0 = csr[j], s1 = csr[j + 1];
        float p0 = __half2float(albh[j * 8 + h]);
        float p1 = __half2float(albh[(j + 1) * 8 + h]);
        unsigned u0 = *(const unsigned*)(hW0q + (size_t)s0 * 256 + l * 4);
        unsigned u1 = *(const unsigned*)(hW0q + (size_t)s1 * 256 + l * 4);
        vf2 a0 = __builtin_amdgcn_cvt_pk_f32_fp8(u0, false);
        vf2 a1 = __builtin_amdgcn_cvt_pk_f32_fp8(u0, true);
        vf2 c0 = __builtin_amdgcn_cvt_pk_f32_fp8(u1, false);
        vf2 c1 = __builtin_amdgcn_cvt_pk_f32_fp8(u1, true);
        acc.x = fmaf(p0, a0[0], acc.x); acc.y = fmaf(p0, a0[1], acc.y);
        acc.z = fmaf(p0, a1[0], acc.z); acc.w = fmaf(p0, a1[1], acc.w);
        acc.x = fmaf(p1, c0[0], acc.x); acc.y = fmaf(p1, c0[1], acc.y);
        acc.z = fmaf(p1, c1[0], acc.z); acc.w = fmaf(p1, c1[1], acc.w);
    }
    if (j < je) {
        int s0 = csr[j];
        float p0 = __half2float(albh[j * 8 + h]);
        unsigned u0 = *(const unsigned*)(hW0q + (size_t)s0 * 256 + l * 4);
        vf2 a0 = __builtin_amdgcn_cvt_pk_f32_fp8(u0, false);
        vf2 a1 = __builtin_amdgcn_cvt_pk_f32_fp8(u0, true);
        acc.x = fmaf(p0, a0[0], acc.x); acc.y = fmaf(p0, a0[1], acc.y);
        acc.z = fmaf(p0, a1[0], acc.z); acc.w = fmaf(p0, a1[1], acc.w);
    }
    const float inv = id0[i * 8 + h] * FP8_INV;
    float4 bg = *(const float4*)(bg0 + l * 4);
    float4 val;
    val.x = fmaf(acc.x, inv, bg.x); val.y = fmaf(acc.y, inv, bg.y);
    val.z = fmaf(acc.z, inv, bg.z); val.w = fmaf(acc.w, inv, bg.w);
    val.x = (val.x > 0.f) ? val.x : expm1f(val.x);
    val.y = (val.y > 0.f) ? val.y : expm1f(val.y);
    val.z = (val.z > 0.f) ? val.z : expm1f(val.z);
    val.w = (val.w > 0.f) ? val.w : expm1f(val.w);
    uint2 ru = *(const uint2*)(resio + (size_t)i * 256 + l * 4);
    float2 r0 = __half22float2(*(const __half2*)&ru.x);
    float2 r1 = __half22float2(*(const __half2*)&ru.y);
    val.x += r0.x; val.y += r0.y; val.z += r1.x; val.w += r1.y;
    float sm = val.x + val.y + val.z + val.w;
#pragma unroll
    for (int o = 32; o >= 1; o >>= 1) sm += __shfl_xor(sm, o);
    float mean = sm * (1.f / 256.f);
    float4 d;
    d.x = val.x - mean; d.y = val.y - mean; d.z = val.z - mean; d.w = val.w - mean;
    float vv = d.x * d.x + d.y * d.y + d.z * d.z + d.w * d.w;
#pragma unroll
    for (int o = 32; o >= 1; o >>= 1) vv += __shfl_xor(vv, o);
    float rstd = rsqrtf(vv * (1.f / 256.f) + LN_EPS);
    float4 gv = *(const float4*)(g0 + l * 4);
    float4 bv = *(const float4*)(b0 + l * 4);
    __half2 o0 = __float22half2_rn(make_float2(fmaf(d.x * rstd, gv.x, bv.x),
                                               fmaf(d.y * rstd, gv.y, bv.y)));
    __half2 o1 = __float22half2_rn(make_float2(fmaf(d.z * rstd, gv.z, bv.z),
                                               fmaf(d.w * rstd, gv.w, bv.w)));
    uint2 ou;
    ou.x = *(unsigned*)&o0; ou.y = *(unsigned*)&o1;
    *(uint2*)(resio + (size_t)i * 256 + l * 4) = ou;
}

// ------------- layer1 linears (h1 fp16 in): kc=t&7, col=t>>3; shuffle-reduced -------------
__global__ __launch_bounds__(256) void k_lin1(const __half* __restrict__ h1h,
    const float* __restrict__ Wr1, const float* __restrict__ br1,
    const float* __restrict__ W1,
    float* __restrict__ res1, __half* __restrict__ hW1h) {
    const int t = threadIdx.x;
    const int kc = t & 7, col = t >> 3;
    float wr[32], wc[32];
#pragma unroll
    for (int j = 0; j < 32; j++) {
        wr[j] = Wr1[(kc * 32 + j) * 32 + col];
        wc[j] = W1[(kc * 32 + j) * 32 + col];
    }
    const float brv = br1[col];
    __shared__ float sh[8 * 288];      // 8 nodes x (8 chunks * 36 padded)
    const int blockBase = blockIdx.x * 64;
    for (int g = 0; g < 8; g++) {
        const int nb = blockBase + g * 8;
        __syncthreads();
#pragma unroll
        for (int r = 0; r < 8; r++) {
            int node = nb + r;
            sh[r * 288 + (t >> 5) * 36 + (t & 31)] =
                (node < N_NODES) ? __half2float(h1h[(size_t)node * 256 + t]) : 0.f;
        }
        __syncthreads();
        for (int r = 0; r < 8; r++) {
            int node = nb + r;
            if (node >= N_NODES) break;
            const float4* lp = (const float4*)(sh + r * 288 + kc * 36);
            float sr = 0.f, sw = 0.f;
#pragma unroll
            for (int q = 0; q < 8; q++) {
                float4 v = lp[q];
                sr = fmaf(v.x, wr[4*q+0], sr); sw = fmaf(v.x, wc[4*q+0], sw);
                sr = fmaf(v.y, wr[4*q+1], sr); sw = fmaf(v.y, wc[4*q+1], sw);
                sr = fmaf(v.z, wr[4*q+2], sr); sw = fmaf(v.z, wc[4*q+2], sw);
                sr = fmaf(v.w, wr[4*q+3], sr); sw = fmaf(v.w, wc[4*q+3], sw);
            }
            sr += __shfl_xor(sr, 1); sw += __shfl_xor(sw, 1);
            sr += __shfl_xor(sr, 2); sw += __shfl_xor(sw, 2);
            sr += __shfl_xor(sr, 4); sw += __shfl_xor(sw, 4);
            if (kc == 0) {
                res1[node * 32 + col] = sr + brv;
                hW1h[node * 32 + col] = __float2half(sw);
            }
        }
    }
}

// ------------- layer1 attention dots from hW1 (fp16) -------------
__global__ __launch_bounds__(256) void k_att1(const __half* __restrict__ hW1h,
    const float* __restrict__ as1, const float* __restrict__ ad1,
    float* __restrict__ a_s1, float* __restrict__ a_d1) {
    const int idx = blockIdx.x * 256 + threadIdx.x;
    const int i = idx >> 5, f = idx & 31;
    float w = __half2float(hW1h[idx]);
    float ps = w * as1[f], pd = w * ad1[f];
#pragma unroll
    for (int o = 16; o >= 1; o >>= 1) { ps += __shfl_xor(ps, o); pd += __shfl_xor(pd, o); }
    if (f == 0) { a_s1[i] = ps; a_d1[i] = pd; }
}

// -------- layer1: fused softmax + aggregation + LN; 8 lanes per node --------
__global__ __launch_bounds__(256) void k_agg1(const int* __restrict__ rowstart,
    const int* __restrict__ csr, const float* __restrict__ a_s1,
    const float* __restrict__ a_d1, const __half* __restrict__ hW1h,
    const float* __restrict__ bg1, const float* __restrict__ res1,
    const float* __restrict__ g1, const float* __restrict__ b1,
    float* __restrict__ h2) {
    const int t = threadIdx.x;
    const int i = blockIdx.x * 32 + (t >> 3);
    const int u = t & 7;
    if (i >= N_NODES) return;
    const int jb = rowstart[i], je = rowstart[i + 1];
    const float ad = a_d1[i];
    float mx = -3.4e38f;
    for (int j = jb + u; j < je; j += 8) {
        float e = a_s1[csr[j]] + ad;
        e = (e > 0.f) ? e : NEG_SLOPE * e;
        mx = fmaxf(mx, e);
    }
    mx = fmaxf(mx, __shfl_xor(mx, 1));
    mx = fmaxf(mx, __shfl_xor(mx, 2));
    mx = fmaxf(mx, __shfl_xor(mx, 4));
    float sum = 0.f;
    for (int j = jb + u; j < je; j += 8) {
        float e = a_s1[csr[j]] + ad;
        e = (e > 0.f) ? e : NEG_SLOPE * e;
        sum += __expf(e - mx);
    }
    sum += __shfl_xor(sum, 1);
    sum += __shfl_xor(sum, 2);
    sum += __shfl_xor(sum, 4);
    const float inv = 1.f / (sum + 1e-16f);
    float4 acc = make_float4(0.f, 0.f, 0.f, 0.f);
    for (int j = jb; j < je; j++) {
        int s = csr[j];
        float e = a_s1[s] + ad;
        e = (e > 0.f) ? e : NEG_SLOPE * e;
        float p = __expf(e - mx);
        uint2 uu = *(const uint2*)(hW1h + s * 32 + u * 4);
        float2 v0 = __half22float2(*(const __half2*)&uu.x);
        float2 v1 = __half22float2(*(const __half2*)&uu.y);
        acc.x = fmaf(p, v0.x, acc.x); acc.y = fmaf(p, v0.y, acc.y);
        acc.z = fmaf(p, v1.x, acc.z); acc.w = fmaf(p, v1.y, acc.w);
    }
    float4 bg = *(const float4*)(bg1 + u * 4);
    float4 rs = *(const float4*)(res1 + i * 32 + u * 4);
    float4 val;
    val.x = fmaf(acc.x, inv, bg.x) + rs.x; val.y = fmaf(acc.y, inv, bg.y) + rs.y;
    val.z = fmaf(acc.z, inv, bg.z) + rs.z; val.w = fmaf(acc.w, inv, bg.w) + rs.w;
    float sm = val.x + val.y + val.z + val.w;
    sm += __shfl_xor(sm, 1); sm += __shfl_xor(sm, 2); sm += __shfl_xor(sm, 4);
    float mean = sm * (1.f / 32.f);
    float4 d;
    d.x = val.x - mean; d.y = val.y - mean; d.z = val.z - mean; d.w = val.w - mean;
    float vv = d.x * d.x + d.y * d.y + d.z * d.z + d.w * d.w;
    vv += __shfl_xor(vv, 1); vv += __shfl_xor(vv, 2); vv += __shfl_xor(vv, 4);
    float rstd = rsqrtf(vv * (1.f / 32.f) + LN_EPS);
    float4 gv = *(const float4*)(g1 + u * 4);
    float4 bv = *(const float4*)(b1 + u * 4);
    float4 outv;
    outv.x = fmaf(d.x * rstd, gv.x, bv.x); outv.y = fmaf(d.y * rstd, gv.y, bv.y);
    outv.z = fmaf(d.z * rstd, gv.z, bv.z); outv.w = fmaf(d.w * rstd, gv.w, bv.w);
    *(float4*)(h2 + i * 32 + u * 4) = outv;
}

// ---------------- global mean pool partials ----------------
__global__ __launch_bounds__(256) void k_pool(const float* __restrict__ h2, float* __restrict__ partial) {
    const int t = threadIdx.x;
    const int col = t & 31, sub = t >> 5;
    float acc = 0.f;
    for (int i = blockIdx.x * 8 + sub; i < N_NODES; i += 64 * 8) acc += h2[i * 32 + col];
    __shared__ float s[256];
    s[t] = acc; __syncthreads();
    if (t < 32) {
        float a = 0.f;
        for (int k = 0; k < 8; k++) a += s[k * 32 + t];
        partial[blockIdx.x * 32 + t] = a;
    }
}

// ---------------- final: pooled @ Wout + bout ----------------
__global__ __launch_bounds__(64) void k_final(const float* __restrict__ partial,
                                              const float* __restrict__ Wout,
                                              const float* __restrict__ bout,
                                              float* __restrict__ out) {
    __shared__ float pooled[32];
    int t = threadIdx.x;
    if (t < 32) {
        float a = 0.f;
        for (int b = 0; b < 64; b++) a += partial[b * 32 + t];
        pooled[t] = a * (1.f / (float)N_NODES);
    }
    __syncthreads();
    if (t < OUTD) {
        float o = bout[t];
        for (int c = 0; c < 32; c++) o = fmaf(pooled[c], Wout[c * OUTD + t], o);
        out[t] = o;
    }
}

extern "C" void kernel_launch(void* const* d_in, const int* in_sizes, int n_in,
                              void* d_out, int out_size, void* d_ws, size_t ws_size,
                              hipStream_t stream) {
    const float* x    = (const float*)d_in[0];
    const int*   eidx = (const int*)d_in[1];      // [0,E)=src, [E,2E)=dst
    const float* Win  = (const float*)d_in[3];
    const float* bin  = (const float*)d_in[4];
    const float* Wr0  = (const float*)d_in[5];
    const float* br0  = (const float*)d_in[6];
    const float* W0   = (const float*)d_in[7];
    const float* as0  = (const float*)d_in[8];
    const float* ad0  = (const float*)d_in[9];
    const float* bg0  = (const float*)d_in[10];
    const float* g0   = (const float*)d_in[11];
    const float* b0   = (const float*)d_in[12];
    const float* Wr1  = (const float*)d_in[13];
    const float* br1  = (const float*)d_in[14];
    const float* W1   = (const float*)d_in[15];
    const float* as1  = (const float*)d_in[16];
    const float* ad1  = (const float*)d_in[17];
    const float* bg1  = (const float*)d_in[18];
    const float* g1   = (const float*)d_in[19];
    const float* b1   = (const float*)d_in[20];
    const float* Wout = (const float*)d_in[21];
    const float* bout = (const float*)d_in[22];
    float* out = (float*)d_out;

    const int* srcA = eidx;
    const int* dstA = eidx + N_EDGES;

    // workspace layout (byte offsets)
    char* B = (char*)d_ws;
    __half* res0h = (__half*)B;                             // N*256 fp16, 25.6 MB (becomes h1)
    unsigned char* hW0q = (unsigned char*)(B + 25600000);   // N*256 fp8, 12.8 MB
    float* a_s0 = (float*)(B + 38400000);                   // N*8
    float* a_d0 = (float*)(B + 40000000);                   // N*8
    float* id0  = (float*)(B + 41600000);                   // N*8
    __half* albh = (__half*)(B + 43200000);                 // (E+N)*8 fp16, 13.6 MB [dead after agg0]
    // layer-1 temps overlay albh region (all strictly after agg0)
    float* res1  = (float*)(B + 43200000);                  // N*32 fp32
    __half* hW1h = (__half*)(B + 49600000);                 // N*32 fp16
    float* a_s1  = (float*)(B + 52800000);                  // N
    float* a_d1  = (float*)(B + 53000000);                  // N
    float* h2    = (float*)(B + 53200000);                  // N*32 fp32
    int* rowstart = (int*)(B + 60000000);                   // N+1
    int* cursor   = (int*)(B + 60200016);                   // N
    int* bsum     = (int*)(B + 60400016);                   // NB0
    int* boff     = (int*)(B + 60400800);                   // NB0
    int* csr      = (int*)(B + 60401600);                   // E+N
    int* deg      = (int*)(B + 63801600);                   // N
    float* partial = (float*)(B + 64001600);                // 64*32

    // dense front (h0 computed on the fly)
    k_lin0<<<(N_NODES + 63) / 64, 256, 0, stream>>>(x, Win, bin, Wr0, br0, W0, as0, ad0,
                                                    res0h, hW0q, a_s0, a_d0);
    // CSR build
    hipMemsetAsync(deg, 0, N_NODES * sizeof(int), stream);
    k_deg_count<<<(N_EDGES + 255) / 256, 256, 0, stream>>>(dstA, deg);
    k_scan1<<<NB0, 256, 0, stream>>>(deg, rowstart, bsum);
    k_scan2<<<1, 256, 0, stream>>>(bsum, rowstart, boff);
    k_scan3<<<NB0, 256, 0, stream>>>(rowstart, boff, cursor);
    k_scatter<<<(N_EDGES + 255) / 256, 256, 0, stream>>>(srcA, dstA, cursor, csr);
    // layer 0
    k_alpha0<<<N_NODES / 4, 256, 0, stream>>>(rowstart, csr, a_s0, a_d0, albh, id0);
    k_agg0<<<N_NODES / 4, 256, 0, stream>>>(rowstart, csr, albh, id0, hW0q, bg0, g0, b0, res0h);
    // layer 1
    k_lin1<<<(N_NODES + 63) / 64, 256, 0, stream>>>(res0h, Wr1, br1, W1, res1, hW1h);
    k_att1<<<(N_NODES * 32) / 256, 256, 0, stream>>>(hW1h, as1, ad1, a_s1, a_d1);
    k_agg1<<<(N_NODES + 31) / 32, 256, 0, stream>>>(rowstart, csr, a_s1, a_d1, hW1h,
                                                    bg1, res1, g1, b1, h2);
    // pool + head
    k_pool<<<64, 256, 0, stream>>>(h2, partial);
    k_final<<<1, 64, 0, stream>>>(partial, Wout, bout, out);
}

// Round 5
// 416.408 us; speedup vs baseline: 1.5657x; 1.1222x over previous
//
#include <hip/hip_runtime.h>
#include <hip/hip_fp16.h>
#include <math.h>

#define N_NODES 50000
#define N_EDGES 800000
#define HEADS 8
#define OUTD 16
#define NEG_SLOPE 0.2f
#define LN_EPS 1e-5f
#define NB0 196           // ceil(N/256)
#define FP8_SCALE 64.f
#define FP8_INV (1.f / 64.f)

typedef float vf2 __attribute__((ext_vector_type(2)));
typedef _Float16 half8 __attribute__((ext_vector_type(8)));
typedef float f32x4 __attribute__((ext_vector_type(4)));

// ------------- layer0: h0 = x*Win+bin on the fly; res0 (fp16), hW0 (fp8 x64),
// attention dots. 256 thr = one output col, 64 nodes/block.
__global__ __launch_bounds__(256) void k_lin0(const float* __restrict__ x,
    const float* __restrict__ Win, const float* __restrict__ bin,
    const float* __restrict__ Wr0, const float* __restrict__ br0,
    const float* __restrict__ W0,  const float* __restrict__ as0,
    const float* __restrict__ ad0,
    __half* __restrict__ res0h, unsigned char* __restrict__ hW0q,
    float* __restrict__ a_s0, float* __restrict__ a_d0) {
    const int t = threadIdx.x;
    const int base = blockIdx.x * 64;
    __shared__ float sx[64];
    __shared__ float lh[64 * 32];
    float wr[32], wc[32];
#pragma unroll
    for (int k = 0; k < 32; k++) { wr[k] = Wr0[k * 256 + t]; wc[k] = W0[k * 256 + t]; }
    const float brv = br0[t], asv = as0[t], adv = ad0[t];
    if (t < 64) sx[t] = (base + t < N_NODES) ? x[base + t] : 0.f;
    __syncthreads();
    const float winv = Win[t & 31], binv = bin[t & 31];
    for (int idx = t; idx < 2048; idx += 256) {
        int m = idx >> 5;
        lh[idx] = fmaf(sx[m], winv, binv);
    }
    __syncthreads();
    int mmax = min(64, N_NODES - base);
    for (int m = 0; m < mmax; m++) {
        int node = base + m;
        const float4* lp = (const float4*)(lh + m * 32);
        float ar = brv, aw = 0.f;
#pragma unroll
        for (int q = 0; q < 8; q++) {
            float4 v = lp[q];
            ar = fmaf(v.x, wr[4*q+0], ar); aw = fmaf(v.x, wc[4*q+0], aw);
            ar = fmaf(v.y, wr[4*q+1], ar); aw = fmaf(v.y, wc[4*q+1], aw);
            ar = fmaf(v.z, wr[4*q+2], ar); aw = fmaf(v.z, wc[4*q+2], aw);
            ar = fmaf(v.w, wr[4*q+3], ar); aw = fmaf(v.w, wc[4*q+3], aw);
        }
        res0h[(size_t)node * 256 + t] = __float2half(ar);
        int pk = __builtin_amdgcn_cvt_pk_fp8_f32(aw * FP8_SCALE, 0.f, 0, false);
        hW0q[(size_t)node * 256 + t] = (unsigned char)(pk & 0xff);
        float ps = aw * asv, pd = aw * adv;
#pragma unroll
        for (int o = 16; o >= 1; o >>= 1) { ps += __shfl_xor(ps, o); pd += __shfl_xor(pd, o); }
        if ((t & 31) == 0) { a_s0[node * 8 + (t >> 5)] = ps; a_d0[node * 8 + (t >> 5)] = pd; }
    }
}

// ---------------- CSR build by dst ----------------
__global__ __launch_bounds__(256) void k_deg_count(const int* __restrict__ dstA, int* deg) {
    int e = blockIdx.x * 256 + threadIdx.x;
    if (e < N_EDGES) atomicAdd(&deg[dstA[e]], 1);
}
__global__ __launch_bounds__(256) void k_scan1(const int* __restrict__ deg,
                                               int* __restrict__ rowstart, int* __restrict__ bsum) {
    __shared__ int s[256];
    int t = threadIdx.x;
    int i = blockIdx.x * 256 + t;
    int v = (i < N_NODES) ? (deg[i] + 1) : 0;   // +1 self-loop
    s[t] = v; __syncthreads();
    for (int o = 1; o < 256; o <<= 1) {
        int xv = (t >= o) ? s[t - o] : 0;
        __syncthreads();
        s[t] += xv;
        __syncthreads();
    }
    if (i < N_NODES) rowstart[i] = s[t] - v;
    if (t == 255) bsum[blockIdx.x] = s[255];
}
__global__ __launch_bounds__(256) void k_scan2(const int* __restrict__ bsum,
                                               int* __restrict__ rowstart, int* __restrict__ boff) {
    __shared__ int s[256];
    int t = threadIdx.x;
    int v = (t < NB0) ? bsum[t] : 0;
    s[t] = v; __syncthreads();
    for (int o = 1; o < 256; o <<= 1) {
        int xv = (t >= o) ? s[t - o] : 0;
        __syncthreads();
        s[t] += xv;
        __syncthreads();
    }
    if (t < NB0) boff[t] = s[t] - v;
    if (t == 255) rowstart[N_NODES] = s[255];   // = E + N
}
__global__ __launch_bounds__(256) void k_scan3(int* __restrict__ rowstart,
                                               const int* __restrict__ boff, int* __restrict__ cursor) {
    int t = threadIdx.x;
    int i = blockIdx.x * 256 + t;
    if (i < N_NODES) {
        int r = rowstart[i] + boff[blockIdx.x];
        rowstart[i] = r;
        cursor[i] = r;
    }
}
__global__ __launch_bounds__(256) void k_scatter(const int* __restrict__ srcA,
                                                 const int* __restrict__ dstA,
                                                 int* cursor, int* __restrict__ csr) {
    int e = blockIdx.x * 256 + threadIdx.x;
    if (e < N_EDGES) {
        int d = dstA[e];
        int p = atomicAdd(&cursor[d], 1);
        csr[p] = srcA[e];
    }
    if (e < N_NODES) {
        int p = atomicAdd(&cursor[e], 1);
        csr[p] = e;
    }
}

// -------- layer0 softmax weights (two-pass recompute, fp16 store) --------
// one wave per node (4 nodes/block); slot=l>>3, h=l&7
__global__ __launch_bounds__(256) void k_alpha0(const int* __restrict__ rowstart,
    const int* __restrict__ csr, const float* __restrict__ a_s0,
    const float* __restrict__ a_d0,
    __half* __restrict__ albh, float* __restrict__ id0) {
    const int t = threadIdx.x;
    const int i = blockIdx.x * 4 + (t >> 6);
    const int l = t & 63;
    const int slot = l >> 3, h = l & 7;
    const int jb = rowstart[i], je = rowstart[i + 1];
    const float ad = a_d0[i * 8 + h];
    float mx = -3.4e38f;
    for (int j = jb + slot; j < je; j += 8) {
        int s = csr[j];
        float e = a_s0[s * 8 + h] + ad;
        e = (e > 0.f) ? e : NEG_SLOPE * e;
        mx = fmaxf(mx, e);
    }
    mx = fmaxf(mx, __shfl_xor(mx, 8));
    mx = fmaxf(mx, __shfl_xor(mx, 16));
    mx = fmaxf(mx, __shfl_xor(mx, 32));
    float sum = 0.f;
    for (int j = jb + slot; j < je; j += 8) {
        int s = csr[j];
        float e = a_s0[s * 8 + h] + ad;
        e = (e > 0.f) ? e : NEG_SLOPE * e;
        float p = __expf(e - mx);
        albh[j * 8 + h] = __float2half(p);
        sum += p;
    }
    sum += __shfl_xor(sum, 8);
    sum += __shfl_xor(sum, 16);
    sum += __shfl_xor(sum, 32);
    if (l < 8) id0[i * 8 + l] = 1.f / (sum + 1e-16f);
}

// -------- layer0 aggregation (fp8 gather): one wave per node --------
__global__ __launch_bounds__(256) void k_agg0(const int* __restrict__ rowstart,
    const int* __restrict__ csr, const __half* __restrict__ albh,
    const float* __restrict__ id0, const unsigned char* __restrict__ hW0q,
    const float* __restrict__ bg0, const float* __restrict__ g0,
    const float* __restrict__ b0, __half* __restrict__ resio) {
    const int t = threadIdx.x;
    const int w = t >> 6, l = t & 63;
    const int i = blockIdx.x * 4 + w;
    const int h = l >> 3;
    const int jb = rowstart[i], je = rowstart[i + 1];
    float4 acc = make_float4(0.f, 0.f, 0.f, 0.f);
    int j = jb;
    for (; j + 1 < je; j += 2) {
        int s0 = csr[j], s1 = csr[j + 1];
        float p0 = __half2float(albh[j * 8 + h]);
        float p1 = __half2float(albh[(j + 1) * 8 + h]);
        unsigned u0 = *(const unsigned*)(hW0q + (size_t)s0 * 256 + l * 4);
        unsigned u1 = *(const unsigned*)(hW0q + (size_t)s1 * 256 + l * 4);
        vf2 a0 = __builtin_amdgcn_cvt_pk_f32_fp8(u0, false);
        vf2 a1 = __builtin_amdgcn_cvt_pk_f32_fp8(u0, true);
        vf2 c0 = __builtin_amdgcn_cvt_pk_f32_fp8(u1, false);
        vf2 c1 = __builtin_amdgcn_cvt_pk_f32_fp8(u1, true);
        acc.x = fmaf(p0, a0[0], acc.x); acc.y = fmaf(p0, a0[1], acc.y);
        acc.z = fmaf(p0, a1[0], acc.z); acc.w = fmaf(p0, a1[1], acc.w);
        acc.x = fmaf(p1, c0[0], acc.x); acc.y = fmaf(p1, c0[1], acc.y);
        acc.z = fmaf(p1, c1[0], acc.z); acc.w = fmaf(p1, c1[1], acc.w);
    }
    if (j < je) {
        int s0 = csr[j];
        float p0 = __half2float(albh[j * 8 + h]);
        unsigned u0 = *(const unsigned*)(hW0q + (size_t)s0 * 256 + l * 4);
        vf2 a0 = __builtin_amdgcn_cvt_pk_f32_fp8(u0, false);
        vf2 a1 = __builtin_amdgcn_cvt_pk_f32_fp8(u0, true);
        acc.x = fmaf(p0, a0[0], acc.x); acc.y = fmaf(p0, a0[1], acc.y);
        acc.z = fmaf(p0, a1[0], acc.z); acc.w = fmaf(p0, a1[1], acc.w);
    }
    const float inv = id0[i * 8 + h] * FP8_INV;
    float4 bg = *(const float4*)(bg0 + l * 4);
    float4 val;
    val.x = fmaf(acc.x, inv, bg.x); val.y = fmaf(acc.y, inv, bg.y);
    val.z = fmaf(acc.z, inv, bg.z); val.w = fmaf(acc.w, inv, bg.w);
    val.x = (val.x > 0.f) ? val.x : expm1f(val.x);
    val.y = (val.y > 0.f) ? val.y : expm1f(val.y);
    val.z = (val.z > 0.f) ? val.z : expm1f(val.z);
    val.w = (val.w > 0.f) ? val.w : expm1f(val.w);
    uint2 ru = *(const uint2*)(resio + (size_t)i * 256 + l * 4);
    float2 r0 = __half22float2(*(const __half2*)&ru.x);
    float2 r1 = __half22float2(*(const __half2*)&ru.y);
    val.x += r0.x; val.y += r0.y; val.z += r1.x; val.w += r1.y;
    float sm = val.x + val.y + val.z + val.w;
#pragma unroll
    for (int o = 32; o >= 1; o >>= 1) sm += __shfl_xor(sm, o);
    float mean = sm * (1.f / 256.f);
    float4 d;
    d.x = val.x - mean; d.y = val.y - mean; d.z = val.z - mean; d.w = val.w - mean;
    float vv = d.x * d.x + d.y * d.y + d.z * d.z + d.w * d.w;
#pragma unroll
    for (int o = 32; o >= 1; o >>= 1) vv += __shfl_xor(vv, o);
    float rstd = rsqrtf(vv * (1.f / 256.f) + LN_EPS);
    float4 gv = *(const float4*)(g0 + l * 4);
    float4 bv = *(const float4*)(b0 + l * 4);
    __half2 o0 = __float22half2_rn(make_float2(fmaf(d.x * rstd, gv.x, bv.x),
                                               fmaf(d.y * rstd, gv.y, bv.y)));
    __half2 o1 = __float22half2_rn(make_float2(fmaf(d.z * rstd, gv.z, bv.z),
                                               fmaf(d.w * rstd, gv.w, bv.w)));
    uint2 ou;
    ou.x = *(unsigned*)&o0; ou.y = *(unsigned*)&o1;
    *(uint2*)(resio + (size_t)i * 256 + l * 4) = ou;
}

// ------------- layer1 linears via MFMA 16x16x32 f16 + fused attention dots -------------
// block = 256 thr = 4 waves; wave w computes 16 nodes x 64 cols ([Wr1|W1] packed).
// B packed in LDS fragment-order: Bs[((kt*4+q)*64 + n)*8 + j] = W[kt*32+q*8+j][n], fp16.
__global__ __launch_bounds__(256) void k_lin1(const __half* __restrict__ h1h,
    const float* __restrict__ Wr1, const float* __restrict__ br1,
    const float* __restrict__ W1,  const float* __restrict__ as1,
    const float* __restrict__ ad1,
    float* __restrict__ res1, __half* __restrict__ hW1h,
    float* __restrict__ a_s1, float* __restrict__ a_d1) {
    const int t = threadIdx.x;
    __shared__ _Float16 Bs[16384];   // 32 KB
    for (int idx = t; idx < 16384; idx += 256) {
        int j = idx & 7;
        int n = (idx >> 3) & 63;
        int qk = idx >> 9;                 // kt*4 + q
        int k = qk * 8 + j;                // = kt*32 + q*8 + j
        float wv = (n < 32) ? Wr1[k * 32 + n] : W1[k * 32 + (n - 32)];
        Bs[idx] = (_Float16)wv;
    }
    __syncthreads();
    const int w = t >> 6, l = t & 63;
    const int q = l >> 4;
    const int nodeA = blockIdx.x * 64 + w * 16 + (l & 15);   // A-frag m index
    const half8* B8 = (const half8*)Bs;
    f32x4 c0 = {0.f, 0.f, 0.f, 0.f}, c1 = c0, c2 = c0, c3 = c0;
#pragma unroll
    for (int kt = 0; kt < 8; kt++) {
        half8 a = {0,0,0,0,0,0,0,0};
        if (nodeA < N_NODES)
            a = *(const half8*)(h1h + (size_t)nodeA * 256 + kt * 32 + q * 8);
        const int bb = (kt * 4 + q) * 64 + (l & 15);
        c0 = __builtin_amdgcn_mfma_f32_16x16x32_f16(a, B8[bb +  0], c0, 0, 0, 0);
        c1 = __builtin_amdgcn_mfma_f32_16x16x32_f16(a, B8[bb + 16], c1, 0, 0, 0);
        c2 = __builtin_amdgcn_mfma_f32_16x16x32_f16(a, B8[bb + 32], c2, 0, 0, 0);
        c3 = __builtin_amdgcn_mfma_f32_16x16x32_f16(a, B8[bb + 48], c3, 0, 0, 0);
    }
    // C/D layout: col = l&15, node = base + w*16 + q*4 + reg
    const int col = l & 15;
    const int nodeE = blockIdx.x * 64 + w * 16 + q * 4;
    const float brv0 = br1[col], brv1 = br1[col + 16];
    const float asv0 = as1[col], asv1 = as1[col + 16];
    const float adv0 = ad1[col], adv1 = ad1[col + 16];
    float ps[4], pd[4];
#pragma unroll
    for (int r = 0; r < 4; r++) {
        int nd = nodeE + r;
        if (nd < N_NODES) {
            res1[nd * 32 + col]      = c0[r] + brv0;
            res1[nd * 32 + col + 16] = c1[r] + brv1;
            hW1h[nd * 32 + col]      = __float2half(c2[r]);
            hW1h[nd * 32 + col + 16] = __float2half(c3[r]);
        }
        ps[r] = c2[r] * asv0 + c3[r] * asv1;
        pd[r] = c2[r] * adv0 + c3[r] * adv1;
    }
#pragma unroll
    for (int o = 1; o <= 8; o <<= 1) {
#pragma unroll
        for (int r = 0; r < 4; r++) {
            ps[r] += __shfl_xor(ps[r], o);
            pd[r] += __shfl_xor(pd[r], o);
        }
    }
    if (col == 0) {
#pragma unroll
        for (int r = 0; r < 4; r++) {
            int nd = nodeE + r;
            if (nd < N_NODES) { a_s1[nd] = ps[r]; a_d1[nd] = pd[r]; }
        }
    }
}

// -------- layer1: fused softmax + aggregation + LN; 8 lanes per node --------
__global__ __launch_bounds__(256) void k_agg1(const int* __restrict__ rowstart,
    const int* __restrict__ csr, const float* __restrict__ a_s1,
    const float* __restrict__ a_d1, const __half* __restrict__ hW1h,
    const float* __restrict__ bg1, const float* __restrict__ res1,
    const float* __restrict__ g1, const float* __restrict__ b1,
    float* __restrict__ h2) {
    const int t = threadIdx.x;
    const int i = blockIdx.x * 32 + (t >> 3);
    const int u = t & 7;
    if (i >= N_NODES) return;
    const int jb = rowstart[i], je = rowstart[i + 1];
    const float ad = a_d1[i];
    float mx = -3.4e38f;
    for (int j = jb + u; j < je; j += 8) {
        float e = a_s1[csr[j]] + ad;
        e = (e > 0.f) ? e : NEG_SLOPE * e;
        mx = fmaxf(mx, e);
    }
    mx = fmaxf(mx, __shfl_xor(mx, 1));
    mx = fmaxf(mx, __shfl_xor(mx, 2));
    mx = fmaxf(mx, __shfl_xor(mx, 4));
    float sum = 0.f;
    for (int j = jb + u; j < je; j += 8) {
        float e = a_s1[csr[j]] + ad;
        e = (e > 0.f) ? e : NEG_SLOPE * e;
        sum += __expf(e - mx);
    }
    sum += __shfl_xor(sum, 1);
    sum += __shfl_xor(sum, 2);
    sum += __shfl_xor(sum, 4);
    const float inv = 1.f / (sum + 1e-16f);
    float4 acc = make_float4(0.f, 0.f, 0.f, 0.f);
    for (int j = jb; j < je; j++) {
        int s = csr[j];
        float e = a_s1[s] + ad;
        e = (e > 0.f) ? e : NEG_SLOPE * e;
        float p = __expf(e - mx);
        uint2 uu = *(const uint2*)(hW1h + s * 32 + u * 4);
        float2 v0 = __half22float2(*(const __half2*)&uu.x);
        float2 v1 = __half22float2(*(const __half2*)&uu.y);
        acc.x = fmaf(p, v0.x, acc.x); acc.y = fmaf(p, v0.y, acc.y);
        acc.z = fmaf(p, v1.x, acc.z); acc.w = fmaf(p, v1.y, acc.w);
    }
    float4 bg = *(const float4*)(bg1 + u * 4);
    float4 rs = *(const float4*)(res1 + i * 32 + u * 4);
    float4 val;
    val.x = fmaf(acc.x, inv, bg.x) + rs.x; val.y = fmaf(acc.y, inv, bg.y) + rs.y;
    val.z = fmaf(acc.z, inv, bg.z) + rs.z; val.w = fmaf(acc.w, inv, bg.w) + rs.w;
    float sm = val.x + val.y + val.z + val.w;
    sm += __shfl_xor(sm, 1); sm += __shfl_xor(sm, 2); sm += __shfl_xor(sm, 4);
    float mean = sm * (1.f / 32.f);
    float4 d;
    d.x = val.x - mean; d.y = val.y - mean; d.z = val.z - mean; d.w = val.w - mean;
    float vv = d.x * d.x + d.y * d.y + d.z * d.z + d.w * d.w;
    vv += __shfl_xor(vv, 1); vv += __shfl_xor(vv, 2); vv += __shfl_xor(vv, 4);
    float rstd = rsqrtf(vv * (1.f / 32.f) + LN_EPS);
    float4 gv = *(const float4*)(g1 + u * 4);
    float4 bv = *(const float4*)(b1 + u * 4);
    float4 outv;
    outv.x = fmaf(d.x * rstd, gv.x, bv.x); outv.y = fmaf(d.y * rstd, gv.y, bv.y);
    outv.z = fmaf(d.z * rstd, gv.z, bv.z); outv.w = fmaf(d.w * rstd, gv.w, bv.w);
    *(float4*)(h2 + i * 32 + u * 4) = outv;
}

// ---------------- global mean pool partials ----------------
__global__ __launch_bounds__(256) void k_pool(const float* __restrict__ h2, float* __restrict__ partial) {
    const int t = threadIdx.x;
    const int col = t & 31, sub = t >> 5;
    float acc = 0.f;
    for (int i = blockIdx.x * 8 + sub; i < N_NODES; i += 64 * 8) acc += h2[i * 32 + col];
    __shared__ float s[256];
    s[t] = acc; __syncthreads();
    if (t < 32) {
        float a = 0.f;
        for (int k = 0; k < 8; k++) a += s[k * 32 + t];
        partial[blockIdx.x * 32 + t] = a;
    }
}

// ---------------- final: pooled @ Wout + bout ----------------
__global__ __launch_bounds__(64) void k_final(const float* __restrict__ partial,
                                              const float* __restrict__ Wout,
                                              const float* __restrict__ bout,
                                              float* __restrict__ out) {
    __shared__ float pooled[32];
    int t = threadIdx.x;
    if (t < 32) {
        float a = 0.f;
        for (int b = 0; b < 64; b++) a += partial[b * 32 + t];
        pooled[t] = a * (1.f / (float)N_NODES);
    }
    __syncthreads();
    if (t < OUTD) {
        float o = bout[t];
        for (int c = 0; c < 32; c++) o = fmaf(pooled[c], Wout[c * OUTD + t], o);
        out[t] = o;
    }
}

extern "C" void kernel_launch(void* const* d_in, const int* in_sizes, int n_in,
                              void* d_out, int out_size, void* d_ws, size_t ws_size,
                              hipStream_t stream) {
    const float* x    = (const float*)d_in[0];
    const int*   eidx = (const int*)d_in[1];      // [0,E)=src, [E,2E)=dst
    const float* Win  = (const float*)d_in[3];
    const float* bin  = (const float*)d_in[4];
    const float* Wr0  = (const float*)d_in[5];
    const float* br0  = (const float*)d_in[6];
    const float* W0   = (const float*)d_in[7];
    const float* as0  = (const float*)d_in[8];
    const float* ad0  = (const float*)d_in[9];
    const float* bg0  = (const float*)d_in[10];
    const float* g0   = (const float*)d_in[11];
    const float* b0   = (const float*)d_in[12];
    const float* Wr1  = (const float*)d_in[13];
    const float* br1  = (const float*)d_in[14];
    const float* W1   = (const float*)d_in[15];
    const float* as1  = (const float*)d_in[16];
    const float* ad1  = (const float*)d_in[17];
    const float* bg1  = (const float*)d_in[18];
    const float* g1   = (const float*)d_in[19];
    const float* b1   = (const float*)d_in[20];
    const float* Wout = (const float*)d_in[21];
    const float* bout = (const float*)d_in[22];
    float* out = (float*)d_out;

    const int* srcA = eidx;
    const int* dstA = eidx + N_EDGES;

    // workspace layout (byte offsets)
    char* B = (char*)d_ws;
    __half* res0h = (__half*)B;                             // N*256 fp16, 25.6 MB (becomes h1)
    unsigned char* hW0q = (unsigned char*)(B + 25600000);   // N*256 fp8, 12.8 MB
    float* a_s0 = (float*)(B + 38400000);                   // N*8
    float* a_d0 = (float*)(B + 40000000);                   // N*8
    float* id0  = (float*)(B + 41600000);                   // N*8
    __half* albh = (__half*)(B + 43200000);                 // (E+N)*8 fp16, 13.6 MB [dead after agg0]
    // layer-1 temps overlay albh region (all strictly after agg0)
    float* res1  = (float*)(B + 43200000);                  // N*32 fp32
    __half* hW1h = (__half*)(B + 49600000);                 // N*32 fp16
    float* a_s1  = (float*)(B + 52800000);                  // N
    float* a_d1  = (float*)(B + 53000000);                  // N
    float* h2    = (float*)(B + 53200000);                  // N*32 fp32
    int* rowstart = (int*)(B + 60000000);                   // N+1
    int* cursor   = (int*)(B + 60200016);                   // N
    int* bsum     = (int*)(B + 60400016);                   // NB0
    int* boff     = (int*)(B + 60400800);                   // NB0
    int* csr      = (int*)(B + 60401600);                   // E+N
    int* deg      = (int*)(B + 63801600);                   // N
    float* partial = (float*)(B + 64001600);                // 64*32

    // dense front (h0 computed on the fly)
    k_lin0<<<(N_NODES + 63) / 64, 256, 0, stream>>>(x, Win, bin, Wr0, br0, W0, as0, ad0,
                                                    res0h, hW0q, a_s0, a_d0);
    // CSR build
    hipMemsetAsync(deg, 0, N_NODES * sizeof(int), stream);
    k_deg_count<<<(N_EDGES + 255) / 256, 256, 0, stream>>>(dstA, deg);
    k_scan1<<<NB0, 256, 0, stream>>>(deg, rowstart, bsum);
    k_scan2<<<1, 256, 0, stream>>>(bsum, rowstart, boff);
    k_scan3<<<NB0, 256, 0, stream>>>(rowstart, boff, cursor);
    k_scatter<<<(N_EDGES + 255) / 256, 256, 0, stream>>>(srcA, dstA, cursor, csr);
    // layer 0
    k_alpha0<<<N_NODES / 4, 256, 0, stream>>>(rowstart, csr, a_s0, a_d0, albh, id0);
    k_agg0<<<N_NODES / 4, 256, 0, stream>>>(rowstart, csr, albh, id0, hW0q, bg0, g0, b0, res0h);
    // layer 1 (MFMA linears with fused attention dots)
    k_lin1<<<(N_NODES + 63) / 64, 256, 0, stream>>>(res0h, Wr1, br1, W1, as1, ad1,
                                                    res1, hW1h, a_s1, a_d1);
    k_agg1<<<(N_NODES + 31) / 32, 256, 0, stream>>>(rowstart, csr, a_s1, a_d1, hW1h,
                                                    bg1, res1, g1, b1, h2);
    // pool + head
    k_pool<<<64, 256, 0, stream>>>(h2, partial);
    k_final<<<1, 64, 0, stream>>>(partial, Wout, bout, out);
}

// Round 6
// 391.376 us; speedup vs baseline: 1.6658x; 1.0640x over previous
//
#include <hip/hip_runtime.h>
#include <hip/hip_fp16.h>
#include <math.h>

#define N_NODES 50000
#define N_EDGES 800000
#define HEADS 8
#define OUTD 16
#define NEG_SLOPE 0.2f
#define LN_EPS 1e-5f
#define NB0 196           // ceil(N/256)
#define FP8_SCALE 64.f
#define FP8_INV (1.f / 64.f)
#define NEGBIG -3.0e38f

typedef float vf2 __attribute__((ext_vector_type(2)));
typedef _Float16 half8 __attribute__((ext_vector_type(8)));
typedef float f32x4 __attribute__((ext_vector_type(4)));

// ------------- layer0 via MFMA: h0 = x*Win+bin built in-register (rank-1);
// res0h = h0@Wr0+br0 (fp16), hW0q = h0@W0 (fp8 x64), fused per-head attention dots.
// block 256 = 4 waves; wave = 16 nodes x 512 cols ([Wr0|W0]); B in LDS frag-order.
__global__ __launch_bounds__(256) void k_lin0(const float* __restrict__ x,
    const float* __restrict__ Win, const float* __restrict__ bin,
    const float* __restrict__ Wr0, const float* __restrict__ br0,
    const float* __restrict__ W0,  const float* __restrict__ as0,
    const float* __restrict__ ad0,
    __half* __restrict__ res0h, unsigned char* __restrict__ hW0q,
    float* __restrict__ a_s0, float* __restrict__ a_d0) {
    const int t = threadIdx.x;
    __shared__ _Float16 Bs[16384];   // 32 KB: Bs[((tile*4+q)*16+n)*8+j] = W[q*8+j][tile*16+n]
    for (int idx = t; idx < 16384; idx += 256) {
        int j = idx & 7;
        int n = (idx >> 3) & 15;
        int q = (idx >> 7) & 3;
        int tile = idx >> 9;
        int col = tile * 16 + n;
        int k = q * 8 + j;
        float wv = (col < 256) ? Wr0[k * 256 + col] : W0[k * 256 + (col - 256)];
        Bs[idx] = (_Float16)wv;
    }
    __syncthreads();
    const int w = t >> 6, l = t & 63;
    const int m = l & 15, q4 = l >> 4;
    const int nodeA = blockIdx.x * 64 + w * 16 + m;
    const float xv = (nodeA < N_NODES) ? x[nodeA] : 0.f;
    half8 a;
#pragma unroll
    for (int j = 0; j < 8; j++) {
        int k = q4 * 8 + j;
        a[j] = (_Float16)fmaf(xv, Win[k], bin[k]);
    }
    const half8* B8 = (const half8*)Bs;
    const int ndBase = blockIdx.x * 64 + w * 16 + q4 * 4;
    // res tiles 0..15
#pragma unroll
    for (int tile = 0; tile < 16; tile++) {
        f32x4 c = {0.f, 0.f, 0.f, 0.f};
        c = __builtin_amdgcn_mfma_f32_16x16x32_f16(a, B8[(tile * 4 + q4) * 16 + m], c, 0, 0, 0);
        const int col = tile * 16 + m;
        const float brv = br0[col];
#pragma unroll
        for (int r = 0; r < 4; r++) {
            int nd = ndBase + r;
            if (nd < N_NODES) res0h[(size_t)nd * 256 + col] = __float2half(c[r] + brv);
        }
    }
    // hW0 tiles 16..31, head-paired for attention dots
#pragma unroll
    for (int h = 0; h < 8; h++) {
        float ps[4] = {0.f, 0.f, 0.f, 0.f}, pd[4] = {0.f, 0.f, 0.f, 0.f};
#pragma unroll
        for (int sub = 0; sub < 2; sub++) {
            const int tile = 16 + h * 2 + sub;
            f32x4 c = {0.f, 0.f, 0.f, 0.f};
            c = __builtin_amdgcn_mfma_f32_16x16x32_f16(a, B8[(tile * 4 + q4) * 16 + m], c, 0, 0, 0);
            const int colW = (h * 2 + sub) * 16 + m;
            const float asv = as0[colW], adv = ad0[colW];
#pragma unroll
            for (int r = 0; r < 4; r++) {
                float aw = c[r];
                int nd = ndBase + r;
                if (nd < N_NODES) {
                    int pk = __builtin_amdgcn_cvt_pk_fp8_f32(aw * FP8_SCALE, 0.f, 0, false);
                    hW0q[(size_t)nd * 256 + colW] = (unsigned char)(pk & 0xff);
                }
                ps[r] = fmaf(aw, asv, ps[r]);
                pd[r] = fmaf(aw, adv, pd[r]);
            }
        }
#pragma unroll
        for (int o = 1; o <= 8; o <<= 1) {
#pragma unroll
            for (int r = 0; r < 4; r++) {
                ps[r] += __shfl_xor(ps[r], o);
                pd[r] += __shfl_xor(pd[r], o);
            }
        }
        if (m == 0) {
#pragma unroll
            for (int r = 0; r < 4; r++) {
                int nd = ndBase + r;
                if (nd < N_NODES) { a_s0[nd * 8 + h] = ps[r]; a_d0[nd * 8 + h] = pd[r]; }
            }
        }
    }
}

// ---------------- CSR build by dst ----------------
__global__ __launch_bounds__(256) void k_deg_count(const int* __restrict__ dstA, int* deg) {
    int e = blockIdx.x * 256 + threadIdx.x;
    if (e < N_EDGES) atomicAdd(&deg[dstA[e]], 1);
}
__global__ __launch_bounds__(256) void k_scan1(const int* __restrict__ deg,
                                               int* __restrict__ rowstart, int* __restrict__ bsum) {
    __shared__ int s[256];
    int t = threadIdx.x;
    int i = blockIdx.x * 256 + t;
    int v = (i < N_NODES) ? (deg[i] + 1) : 0;   // +1 self-loop
    s[t] = v; __syncthreads();
    for (int o = 1; o < 256; o <<= 1) {
        int xv = (t >= o) ? s[t - o] : 0;
        __syncthreads();
        s[t] += xv;
        __syncthreads();
    }
    if (i < N_NODES) rowstart[i] = s[t] - v;
    if (t == 255) bsum[blockIdx.x] = s[255];
}
__global__ __launch_bounds__(256) void k_scan2(const int* __restrict__ bsum,
                                               int* __restrict__ rowstart, int* __restrict__ boff) {
    __shared__ int s[256];
    int t = threadIdx.x;
    int v = (t < NB0) ? bsum[t] : 0;
    s[t] = v; __syncthreads();
    for (int o = 1; o < 256; o <<= 1) {
        int xv = (t >= o) ? s[t - o] : 0;
        __syncthreads();
        s[t] += xv;
        __syncthreads();
    }
    if (t < NB0) boff[t] = s[t] - v;
    if (t == 255) rowstart[N_NODES] = s[255];   // = E + N
}
__global__ __launch_bounds__(256) void k_scan3(int* __restrict__ rowstart,
                                               const int* __restrict__ boff, int* __restrict__ cursor) {
    int t = threadIdx.x;
    int i = blockIdx.x * 256 + t;
    if (i < N_NODES) {
        int r = rowstart[i] + boff[blockIdx.x];
        rowstart[i] = r;
        cursor[i] = r;
    }
}
__global__ __launch_bounds__(256) void k_scatter(const int* __restrict__ srcA,
                                                 const int* __restrict__ dstA,
                                                 int* cursor, int* __restrict__ csr) {
    int e = blockIdx.x * 256 + threadIdx.x;
    if (e < N_EDGES) {
        int d = dstA[e];
        int p = atomicAdd(&cursor[d], 1);
        csr[p] = srcA[e];
    }
    if (e < N_NODES) {
        int p = atomicAdd(&cursor[e], 1);
        csr[p] = e;
    }
}

// -------- layer0: fused online-softmax + fp8 gather-aggregate + ELU + residual + LN --------
// one wave per node (4/block). Pass A: slot=l>>3,h=l&7 online (m,l). Pass B: lane l -> feats 4l.
__global__ __launch_bounds__(256) void k_agg0(const int* __restrict__ rowstart,
    const int* __restrict__ csr, const float* __restrict__ a_s0,
    const float* __restrict__ a_d0, const unsigned char* __restrict__ hW0q,
    const float* __restrict__ bg0, const float* __restrict__ g0,
    const float* __restrict__ b0, __half* __restrict__ resio) {
    const int t = threadIdx.x;
    const int w = t >> 6, l = t & 63;
    const int i = blockIdx.x * 4 + w;
    const int jb = rowstart[i], je = rowstart[i + 1];
    // ---- pass A: online softmax stats per head ----
    const int slot = l >> 3, h = l & 7;
    const float ad = a_d0[i * 8 + h];
    float mx = NEGBIG, lsum = 0.f;
    for (int j = jb + slot; j < je; j += 8) {
        int s = csr[j];
        float e = a_s0[s * 8 + h] + ad;
        e = (e > 0.f) ? e : NEG_SLOPE * e;
        float nm = fmaxf(mx, e);
        lsum = lsum * __expf(mx - nm) + __expf(e - nm);
        mx = nm;
    }
#pragma unroll
    for (int o = 8; o <= 32; o <<= 1) {
        float mo = __shfl_xor(mx, o);
        float lo = __shfl_xor(lsum, o);
        float nm = fmaxf(mx, mo);
        lsum = lsum * __expf(mx - nm) + lo * __expf(mo - nm);
        mx = nm;
    }
    float inv = 1.f / (lsum + 1e-16f);
    // ---- pass B: weighted fp8 row gather; lane l covers feats 4l..4l+3, head l>>3 ----
    const int h2 = l >> 3;
    const float mxb = __shfl(mx, h2);
    const float invb = __shfl(inv, h2) * FP8_INV;
    const float adb = __shfl(ad, h2);
    float4 acc = make_float4(0.f, 0.f, 0.f, 0.f);
    int j = jb;
    for (; j + 3 < je; j += 4) {
        int s0 = csr[j], s1 = csr[j + 1], s2 = csr[j + 2], s3 = csr[j + 3];
        float e0 = a_s0[s0 * 8 + h2] + adb;
        float e1 = a_s0[s1 * 8 + h2] + adb;
        float e2 = a_s0[s2 * 8 + h2] + adb;
        float e3 = a_s0[s3 * 8 + h2] + adb;
        unsigned u0 = *(const unsigned*)(hW0q + (size_t)s0 * 256 + l * 4);
        unsigned u1 = *(const unsigned*)(hW0q + (size_t)s1 * 256 + l * 4);
        unsigned u2 = *(const unsigned*)(hW0q + (size_t)s2 * 256 + l * 4);
        unsigned u3 = *(const unsigned*)(hW0q + (size_t)s3 * 256 + l * 4);
        e0 = (e0 > 0.f) ? e0 : NEG_SLOPE * e0;
        e1 = (e1 > 0.f) ? e1 : NEG_SLOPE * e1;
        e2 = (e2 > 0.f) ? e2 : NEG_SLOPE * e2;
        e3 = (e3 > 0.f) ? e3 : NEG_SLOPE * e3;
        float p0 = __expf(e0 - mxb), p1 = __expf(e1 - mxb);
        float p2 = __expf(e2 - mxb), p3 = __expf(e3 - mxb);
        vf2 a0 = __builtin_amdgcn_cvt_pk_f32_fp8(u0, false);
        vf2 a1 = __builtin_amdgcn_cvt_pk_f32_fp8(u0, true);
        vf2 b0v = __builtin_amdgcn_cvt_pk_f32_fp8(u1, false);
        vf2 b1v = __builtin_amdgcn_cvt_pk_f32_fp8(u1, true);
        vf2 c0v = __builtin_amdgcn_cvt_pk_f32_fp8(u2, false);
        vf2 c1v = __builtin_amdgcn_cvt_pk_f32_fp8(u2, true);
        vf2 d0v = __builtin_amdgcn_cvt_pk_f32_fp8(u3, false);
        vf2 d1v = __builtin_amdgcn_cvt_pk_f32_fp8(u3, true);
        acc.x = fmaf(p0, a0[0], acc.x); acc.y = fmaf(p0, a0[1], acc.y);
        acc.z = fmaf(p0, a1[0], acc.z); acc.w = fmaf(p0, a1[1], acc.w);
        acc.x = fmaf(p1, b0v[0], acc.x); acc.y = fmaf(p1, b0v[1], acc.y);
        acc.z = fmaf(p1, b1v[0], acc.z); acc.w = fmaf(p1, b1v[1], acc.w);
        acc.x = fmaf(p2, c0v[0], acc.x); acc.y = fmaf(p2, c0v[1], acc.y);
        acc.z = fmaf(p2, c1v[0], acc.z); acc.w = fmaf(p2, c1v[1], acc.w);
        acc.x = fmaf(p3, d0v[0], acc.x); acc.y = fmaf(p3, d0v[1], acc.y);
        acc.z = fmaf(p3, d1v[0], acc.z); acc.w = fmaf(p3, d1v[1], acc.w);
    }
    for (; j < je; j++) {
        int s0 = csr[j];
        float e0 = a_s0[s0 * 8 + h2] + adb;
        e0 = (e0 > 0.f) ? e0 : NEG_SLOPE * e0;
        float p0 = __expf(e0 - mxb);
        unsigned u0 = *(const unsigned*)(hW0q + (size_t)s0 * 256 + l * 4);
        vf2 a0 = __builtin_amdgcn_cvt_pk_f32_fp8(u0, false);
        vf2 a1 = __builtin_amdgcn_cvt_pk_f32_fp8(u0, true);
        acc.x = fmaf(p0, a0[0], acc.x); acc.y = fmaf(p0, a0[1], acc.y);
        acc.z = fmaf(p0, a1[0], acc.z); acc.w = fmaf(p0, a1[1], acc.w);
    }
    float4 bg = *(const float4*)(bg0 + l * 4);
    float4 val;
    val.x = fmaf(acc.x, invb, bg.x); val.y = fmaf(acc.y, invb, bg.y);
    val.z = fmaf(acc.z, invb, bg.z); val.w = fmaf(acc.w, invb, bg.w);
    val.x = (val.x > 0.f) ? val.x : expm1f(val.x);
    val.y = (val.y > 0.f) ? val.y : expm1f(val.y);
    val.z = (val.z > 0.f) ? val.z : expm1f(val.z);
    val.w = (val.w > 0.f) ? val.w : expm1f(val.w);
    uint2 ru = *(const uint2*)(resio + (size_t)i * 256 + l * 4);
    float2 r0 = __half22float2(*(const __half2*)&ru.x);
    float2 r1 = __half22float2(*(const __half2*)&ru.y);
    val.x += r0.x; val.y += r0.y; val.z += r1.x; val.w += r1.y;
    float sm = val.x + val.y + val.z + val.w;
#pragma unroll
    for (int o = 32; o >= 1; o >>= 1) sm += __shfl_xor(sm, o);
    float mean = sm * (1.f / 256.f);
    float4 d;
    d.x = val.x - mean; d.y = val.y - mean; d.z = val.z - mean; d.w = val.w - mean;
    float vv = d.x * d.x + d.y * d.y + d.z * d.z + d.w * d.w;
#pragma unroll
    for (int o = 32; o >= 1; o >>= 1) vv += __shfl_xor(vv, o);
    float rstd = rsqrtf(vv * (1.f / 256.f) + LN_EPS);
    float4 gv = *(const float4*)(g0 + l * 4);
    float4 bv = *(const float4*)(b0 + l * 4);
    __half2 o0 = __float22half2_rn(make_float2(fmaf(d.x * rstd, gv.x, bv.x),
                                               fmaf(d.y * rstd, gv.y, bv.y)));
    __half2 o1 = __float22half2_rn(make_float2(fmaf(d.z * rstd, gv.z, bv.z),
                                               fmaf(d.w * rstd, gv.w, bv.w)));
    uint2 ou;
    ou.x = *(unsigned*)&o0; ou.y = *(unsigned*)&o1;
    *(uint2*)(resio + (size_t)i * 256 + l * 4) = ou;
}

// ------------- layer1 linears via MFMA 16x16x32 f16 + fused attention dots -------------
__global__ __launch_bounds__(256) void k_lin1(const __half* __restrict__ h1h,
    const float* __restrict__ Wr1, const float* __restrict__ br1,
    const float* __restrict__ W1,  const float* __restrict__ as1,
    const float* __restrict__ ad1,
    float* __restrict__ res1, __half* __restrict__ hW1h,
    float* __restrict__ a_s1, float* __restrict__ a_d1) {
    const int t = threadIdx.x;
    __shared__ _Float16 Bs[16384];   // 32 KB
    for (int idx = t; idx < 16384; idx += 256) {
        int j = idx & 7;
        int n = (idx >> 3) & 63;
        int qk = idx >> 9;                 // kt*4 + q
        int k = qk * 8 + j;                // = kt*32 + q*8 + j
        float wv = (n < 32) ? Wr1[k * 32 + n] : W1[k * 32 + (n - 32)];
        Bs[idx] = (_Float16)wv;
    }
    __syncthreads();
    const int w = t >> 6, l = t & 63;
    const int q = l >> 4;
    const int nodeA = blockIdx.x * 64 + w * 16 + (l & 15);   // A-frag m index
    const half8* B8 = (const half8*)Bs;
    f32x4 c0 = {0.f, 0.f, 0.f, 0.f}, c1 = c0, c2 = c0, c3 = c0;
#pragma unroll
    for (int kt = 0; kt < 8; kt++) {
        half8 a = {0,0,0,0,0,0,0,0};
        if (nodeA < N_NODES)
            a = *(const half8*)(h1h + (size_t)nodeA * 256 + kt * 32 + q * 8);
        const int bb = (kt * 4 + q) * 64 + (l & 15);
        c0 = __builtin_amdgcn_mfma_f32_16x16x32_f16(a, B8[bb +  0], c0, 0, 0, 0);
        c1 = __builtin_amdgcn_mfma_f32_16x16x32_f16(a, B8[bb + 16], c1, 0, 0, 0);
        c2 = __builtin_amdgcn_mfma_f32_16x16x32_f16(a, B8[bb + 32], c2, 0, 0, 0);
        c3 = __builtin_amdgcn_mfma_f32_16x16x32_f16(a, B8[bb + 48], c3, 0, 0, 0);
    }
    const int col = l & 15;
    const int nodeE = blockIdx.x * 64 + w * 16 + q * 4;
    const float brv0 = br1[col], brv1 = br1[col + 16];
    const float asv0 = as1[col], asv1 = as1[col + 16];
    const float adv0 = ad1[col], adv1 = ad1[col + 16];
    float ps[4], pd[4];
#pragma unroll
    for (int r = 0; r < 4; r++) {
        int nd = nodeE + r;
        if (nd < N_NODES) {
            res1[nd * 32 + col]      = c0[r] + brv0;
            res1[nd * 32 + col + 16] = c1[r] + brv1;
            hW1h[nd * 32 + col]      = __float2half(c2[r]);
            hW1h[nd * 32 + col + 16] = __float2half(c3[r]);
        }
        ps[r] = c2[r] * asv0 + c3[r] * asv1;
        pd[r] = c2[r] * adv0 + c3[r] * adv1;
    }
#pragma unroll
    for (int o = 1; o <= 8; o <<= 1) {
#pragma unroll
        for (int r = 0; r < 4; r++) {
            ps[r] += __shfl_xor(ps[r], o);
            pd[r] += __shfl_xor(pd[r], o);
        }
    }
    if (col == 0) {
#pragma unroll
        for (int r = 0; r < 4; r++) {
            int nd = nodeE + r;
            if (nd < N_NODES) { a_s1[nd] = ps[r]; a_d1[nd] = pd[r]; }
        }
    }
}

// -------- layer1: fused softmax + aggregation + LN; ONE WAVE per node --------
// Pass A: online (m,l) over 64-lane-strided edges. Pass B: 8 edges in parallel
// (slot=l>>3), feats via u=l&7 (float4 each).
__global__ __launch_bounds__(256) void k_agg1(const int* __restrict__ rowstart,
    const int* __restrict__ csr, const float* __restrict__ a_s1,
    const float* __restrict__ a_d1, const __half* __restrict__ hW1h,
    const float* __restrict__ bg1, const float* __restrict__ res1,
    const float* __restrict__ g1, const float* __restrict__ b1,
    float* __restrict__ h2) {
    const int t = threadIdx.x;
    const int w = t >> 6, l = t & 63;
    const int i = blockIdx.x * 4 + w;
    const int jb = rowstart[i], je = rowstart[i + 1];
    const float ad = a_d1[i];
    float mx = NEGBIG, lsum = 0.f;
    for (int j = jb + l; j < je; j += 64) {
        float e = a_s1[csr[j]] + ad;
        e = (e > 0.f) ? e : NEG_SLOPE * e;
        float nm = fmaxf(mx, e);
        lsum = lsum * __expf(mx - nm) + __expf(e - nm);
        mx = nm;
    }
#pragma unroll
    for (int o = 1; o <= 32; o <<= 1) {
        float mo = __shfl_xor(mx, o);
        float lo = __shfl_xor(lsum, o);
        float nm = fmaxf(mx, mo);
        lsum = lsum * __expf(mx - nm) + lo * __expf(mo - nm);
        mx = nm;
    }
    const float inv = 1.f / (lsum + 1e-16f);
    const int slot = l >> 3, u = l & 7;
    float4 acc = make_float4(0.f, 0.f, 0.f, 0.f);
    for (int j = jb + slot; j < je; j += 8) {
        int s = csr[j];
        float e = a_s1[s] + ad;
        e = (e > 0.f) ? e : NEG_SLOPE * e;
        float p = __expf(e - mx);
        uint2 uu = *(const uint2*)(hW1h + s * 32 + u * 4);
        float2 v0 = __half22float2(*(const __half2*)&uu.x);
        float2 v1 = __half22float2(*(const __half2*)&uu.y);
        acc.x = fmaf(p, v0.x, acc.x); acc.y = fmaf(p, v0.y, acc.y);
        acc.z = fmaf(p, v1.x, acc.z); acc.w = fmaf(p, v1.y, acc.w);
    }
#pragma unroll
    for (int o = 8; o <= 32; o <<= 1) {
        acc.x += __shfl_xor(acc.x, o); acc.y += __shfl_xor(acc.y, o);
        acc.z += __shfl_xor(acc.z, o); acc.w += __shfl_xor(acc.w, o);
    }
    float4 bg = *(const float4*)(bg1 + u * 4);
    float4 rs = *(const float4*)(res1 + i * 32 + u * 4);
    float4 val;
    val.x = fmaf(acc.x, inv, bg.x) + rs.x; val.y = fmaf(acc.y, inv, bg.y) + rs.y;
    val.z = fmaf(acc.z, inv, bg.z) + rs.z; val.w = fmaf(acc.w, inv, bg.w) + rs.w;
    float sm = val.x + val.y + val.z + val.w;
    sm += __shfl_xor(sm, 1); sm += __shfl_xor(sm, 2); sm += __shfl_xor(sm, 4);
    float mean = sm * (1.f / 32.f);
    float4 d;
    d.x = val.x - mean; d.y = val.y - mean; d.z = val.z - mean; d.w = val.w - mean;
    float vv = d.x * d.x + d.y * d.y + d.z * d.z + d.w * d.w;
    vv += __shfl_xor(vv, 1); vv += __shfl_xor(vv, 2); vv += __shfl_xor(vv, 4);
    float rstd = rsqrtf(vv * (1.f / 32.f) + LN_EPS);
    float4 gv = *(const float4*)(g1 + u * 4);
    float4 bv = *(const float4*)(b1 + u * 4);
    float4 outv;
    outv.x = fmaf(d.x * rstd, gv.x, bv.x); outv.y = fmaf(d.y * rstd, gv.y, bv.y);
    outv.z = fmaf(d.z * rstd, gv.z, bv.z); outv.w = fmaf(d.w * rstd, gv.w, bv.w);
    if (l < 8) *(float4*)(h2 + i * 32 + u * 4) = outv;
}

// ---------------- global mean pool partials ----------------
__global__ __launch_bounds__(256) void k_pool(const float* __restrict__ h2, float* __restrict__ partial) {
    const int t = threadIdx.x;
    const int col = t & 31, sub = t >> 5;
    float acc = 0.f;
    for (int i = blockIdx.x * 8 + sub; i < N_NODES; i += 64 * 8) acc += h2[i * 32 + col];
    __shared__ float s[256];
    s[t] = acc; __syncthreads();
    if (t < 32) {
        float a = 0.f;
        for (int k = 0; k < 8; k++) a += s[k * 32 + t];
        partial[blockIdx.x * 32 + t] = a;
    }
}

// ---------------- final: pooled @ Wout + bout ----------------
__global__ __launch_bounds__(64) void k_final(const float* __restrict__ partial,
                                              const float* __restrict__ Wout,
                                              const float* __restrict__ bout,
                                              float* __restrict__ out) {
    __shared__ float pooled[32];
    int t = threadIdx.x;
    if (t < 32) {
        float a = 0.f;
        for (int b = 0; b < 64; b++) a += partial[b * 32 + t];
        pooled[t] = a * (1.f / (float)N_NODES);
    }
    __syncthreads();
    if (t < OUTD) {
        float o = bout[t];
        for (int c = 0; c < 32; c++) o = fmaf(pooled[c], Wout[c * OUTD + t], o);
        out[t] = o;
    }
}

extern "C" void kernel_launch(void* const* d_in, const int* in_sizes, int n_in,
                              void* d_out, int out_size, void* d_ws, size_t ws_size,
                              hipStream_t stream) {
    const float* x    = (const float*)d_in[0];
    const int*   eidx = (const int*)d_in[1];      // [0,E)=src, [E,2E)=dst
    const float* Win  = (const float*)d_in[3];
    const float* bin  = (const float*)d_in[4];
    const float* Wr0  = (const float*)d_in[5];
    const float* br0  = (const float*)d_in[6];
    const float* W0   = (const float*)d_in[7];
    const float* as0  = (const float*)d_in[8];
    const float* ad0  = (const float*)d_in[9];
    const float* bg0  = (const float*)d_in[10];
    const float* g0   = (const float*)d_in[11];
    const float* b0   = (const float*)d_in[12];
    const float* Wr1  = (const float*)d_in[13];
    const float* br1  = (const float*)d_in[14];
    const float* W1   = (const float*)d_in[15];
    const float* as1  = (const float*)d_in[16];
    const float* ad1  = (const float*)d_in[17];
    const float* bg1  = (const float*)d_in[18];
    const float* g1   = (const float*)d_in[19];
    const float* b1   = (const float*)d_in[20];
    const float* Wout = (const float*)d_in[21];
    const float* bout = (const float*)d_in[22];
    float* out = (float*)d_out;

    const int* srcA = eidx;
    const int* dstA = eidx + N_EDGES;

    // workspace layout (byte offsets)
    char* B = (char*)d_ws;
    __half* res0h = (__half*)B;                             // N*256 fp16, 25.6 MB (becomes h1)
    unsigned char* hW0q = (unsigned char*)(B + 25600000);   // N*256 fp8, 12.8 MB
    float* a_s0 = (float*)(B + 38400000);                   // N*8
    float* a_d0 = (float*)(B + 40000000);                   // N*8
    // layer-1 temps (region reused; all strictly after agg0)
    float* res1  = (float*)(B + 43200000);                  // N*32 fp32
    __half* hW1h = (__half*)(B + 49600000);                 // N*32 fp16
    float* a_s1  = (float*)(B + 52800000);                  // N
    float* a_d1  = (float*)(B + 53000000);                  // N
    float* h2    = (float*)(B + 53200000);                  // N*32 fp32
    int* rowstart = (int*)(B + 60000000);                   // N+1
    int* cursor   = (int*)(B + 60200016);                   // N
    int* bsum     = (int*)(B + 60400016);                   // NB0
    int* boff     = (int*)(B + 60400800);                   // NB0
    int* csr      = (int*)(B + 60401600);                   // E+N
    int* deg      = (int*)(B + 63801600);                   // N
    float* partial = (float*)(B + 64001600);                // 64*32

    // dense front (MFMA; h0 built in-register)
    k_lin0<<<(N_NODES + 63) / 64, 256, 0, stream>>>(x, Win, bin, Wr0, br0, W0, as0, ad0,
                                                    res0h, hW0q, a_s0, a_d0);
    // CSR build
    hipMemsetAsync(deg, 0, N_NODES * sizeof(int), stream);
    k_deg_count<<<(N_EDGES + 255) / 256, 256, 0, stream>>>(dstA, deg);
    k_scan1<<<NB0, 256, 0, stream>>>(deg, rowstart, bsum);
    k_scan2<<<1, 256, 0, stream>>>(bsum, rowstart, boff);
    k_scan3<<<NB0, 256, 0, stream>>>(rowstart, boff, cursor);
    k_scatter<<<(N_EDGES + 255) / 256, 256, 0, stream>>>(srcA, dstA, cursor, csr);
    // layer 0 (fused softmax + aggregation)
    k_agg0<<<N_NODES / 4, 256, 0, stream>>>(rowstart, csr, a_s0, a_d0, hW0q, bg0, g0, b0, res0h);
    // layer 1
    k_lin1<<<(N_NODES + 63) / 64, 256, 0, stream>>>(res0h, Wr1, br1, W1, as1, ad1,
                                                    res1, hW1h, a_s1, a_d1);
    k_agg1<<<N_NODES / 4, 256, 0, stream>>>(rowstart, csr, a_s1, a_d1, hW1h,
                                            bg1, res1, g1, b1, h2);
    // pool + head
    k_pool<<<64, 256, 0, stream>>>(h2, partial);
    k_final<<<1, 64, 0, stream>>>(partial, Wout, bout, out);
}